// Round 3
// baseline (210.317 us; speedup 1.0000x reference)
//
#include <hip/hip_runtime.h>

// PixelPropagationModule  out = gamma * (softmax(qk^T) @ v^T)^T + x
// B=8, C=256, CI=64, N=3136 (56x56), fp32 in/out.
// R9b: R9 with compile fix — __builtin_nontemporal_store needs a clang
//      ext_vector type, not HIP_vector_type ushort4 (us4 typedef).
// R9: attn counted-waitcnt pipeline (T3/T4).
//     - Raw __builtin_amdgcn_s_barrier() + asm lgkmcnt(0) + sched_barrier(0)
//       fences replace __syncthreads(): no vmcnt(0) drain at the barrier, so
//       prefetch loads stay in flight across steps (compiler emits counted
//       vmcnt at the consumers).
//     - V prefetch 2 steps deep (prA/prB named reg sets, static parity via
//       2-step unrolled loop); K 1 step deep (krA/krB).
//     - op/lp stores nontemporal: the 58MB partial-O write stream no longer
//       evicts the ~2.4MB/XCD K/V working set from L2.
//     Structure otherwise = R8: wave = 16q x 256ch dedup, 64q blocks,
//     grid B*49*JS, XCD swizzle b=bx&7, double-buffered permuted V LDS.
//     pre/proj/reduce unchanged.

constexpr int B_  = 8;
constexpr int C_  = 256;
constexpr int CI_ = 64;
constexpr int N_  = 3136;
constexpr int JS  = 4;        // attn j-split
constexpr int JT  = 32;       // attn j per step
constexpr int VSP = 40;       // V LDS row pitch (ushorts) = 80 B
constexpr int PN  = 64;       // proj pixel tile
constexpr int XSP = C_ + 8;   // proj LDS row pitch

typedef __attribute__((ext_vector_type(8))) short short8;   // 8 bf16 (4 VGPR)
typedef __attribute__((ext_vector_type(4))) float f32x4;
typedef __attribute__((ext_vector_type(4))) ushort us4;     // clang vec (nt-store ok)

static __device__ inline ushort f2b(float f) {               // fp32 -> bf16 (RNE)
    unsigned u = __float_as_uint(f);
    return (ushort)((u + 0x7fffu + ((u >> 16) & 1u)) >> 16);
}
static __device__ inline float b2f(ushort h) {
    return __uint_as_float(((unsigned)h) << 16);
}

// blocks [0, B_*196): x[B][C][N] f32 -> xT[B][N][C] bf16 (LDS transpose)
// blocks [B_*196, +256): Wq/Wk -> wqk[128][256], Wv -> wv[256][256] bf16
__global__ __launch_bounds__(256)
void pre_kernel(const float* __restrict__ x,
                const float* __restrict__ Wq, const float* __restrict__ Wk,
                const float* __restrict__ Wv,
                ushort* __restrict__ xT, ushort* __restrict__ wqk, ushort* __restrict__ wv)
{
    __shared__ float ts[64][65];
    const int bx  = blockIdx.x;
    const int tid = threadIdx.x;

    if (bx >= B_ * 196) {                            // weight convert
        int i = (bx - B_ * 196) * 256 + tid;
        if (i < 16384)      wqk[i] = f2b(Wq[i]);
        else if (i < 32768) wqk[i] = f2b(Wk[i - 16384]);
        wv[i] = f2b(Wv[i]);
        return;
    }

    const int b  = bx / 196;
    const int rm = bx % 196;
    const int n0 = (rm >> 2) * 64;
    const int c0 = (rm & 3) * 64;

    const float* src = x + ((size_t)b * C_ + c0) * N_ + n0;
    #pragma unroll
    for (int rep = 0; rep < 16; rep++) {             // 4096 floats in
        int e = rep * 256 + tid;
        int c = e >> 6, n = e & 63;
        ts[c][n] = src[(size_t)c * N_ + n];
    }
    __syncthreads();
    ushort* dst = xT + ((size_t)b * N_ + n0) * C_ + c0;
    #pragma unroll
    for (int rep = 0; rep < 8; rep++) {              // 2048 ushort2 out
        int e = rep * 256 + tid;
        int n = e >> 5, c2 = (e & 31) * 2;
        ushort2 o;
        o.x = f2b(ts[c2][n]);
        o.y = f2b(ts[c2 + 1][n]);
        *(ushort2*)(dst + (size_t)n * C_ + c2) = o;
    }
}

__global__ __launch_bounds__(256)
void proj_kernel(const ushort* __restrict__ xT, const ushort* __restrict__ wqk,
                 const ushort* __restrict__ wv,
                 const float* __restrict__ bq, const float* __restrict__ bk,
                 const float* __restrict__ bv,
                 ushort* __restrict__ qb, ushort* __restrict__ kb, ushort* __restrict__ vt)
{
    __shared__ ushort xs[PN][XSP];        // 33792 B
    const int b   = blockIdx.x / 49;
    const int n0  = (blockIdx.x % 49) * PN;
    const int tid = threadIdx.x;
    const int w    = tid >> 6;
    const int lane = tid & 63;
    const int m16  = lane & 15;
    const int quad = lane >> 4;

    // stage xT tile [64 pixels][256 c] bf16
    {
        const ushort* src = xT + ((size_t)b * N_ + n0) * C_;
        #pragma unroll
        for (int rep = 0; rep < 8; rep++) {
            int e = rep * 256 + tid;
            int row = e >> 5, ch = (e & 31) * 8;
            *(short8*)&xs[row][ch] = *(const short8*)(src + (size_t)row * C_ + ch);
        }
    }
    __syncthreads();

    // ---- QK GEMM: C[o][pixel]; waves 0,1 -> Q halves, 2,3 -> K halves ----
    {
        f32x4 acc[2][4];
        #pragma unroll
        for (int mt = 0; mt < 2; mt++)
            #pragma unroll
            for (int nt = 0; nt < 4; nt++) acc[mt][nt] = (f32x4){0.f, 0.f, 0.f, 0.f};

        #pragma unroll
        for (int kk = 0; kk < 8; kk++) {
            short8 af[2];
            #pragma unroll
            for (int mt = 0; mt < 2; mt++)   // A[m=o][k=c] = wqk row (L2-hot)
                af[mt] = *(const short8*)(wqk + (size_t)(w * 32 + mt * 16 + m16) * C_ + kk * 32 + quad * 8);
            #pragma unroll
            for (int nt = 0; nt < 4; nt++) {
                short8 bf = *(const short8*)&xs[nt * 16 + m16][kk * 32 + quad * 8];  // B[k=c][n=pix]
                #pragma unroll
                for (int mt = 0; mt < 2; mt++)
                    acc[mt][nt] = __builtin_amdgcn_mfma_f32_16x16x32_bf16(af[mt], bf, acc[mt][nt], 0, 0, 0);
            }
        }
        const float* bias = (w < 2) ? bq : bk;
        ushort* dst = (w < 2) ? qb : kb;
        const int obase = (w & 1) * 32;
        #pragma unroll
        for (int mt = 0; mt < 2; mt++) {
            f32x4 bs = *(const f32x4*)(bias + obase + mt * 16 + quad * 4);
            #pragma unroll
            for (int nt = 0; nt < 4; nt++) {
                us4 pk;
                pk.x = f2b(acc[mt][nt][0] + bs[0]);
                pk.y = f2b(acc[mt][nt][1] + bs[1]);
                pk.z = f2b(acc[mt][nt][2] + bs[2]);
                pk.w = f2b(acc[mt][nt][3] + bs[3]);
                *(us4*)(dst + ((size_t)b * N_ + n0 + nt * 16 + m16) * CI_ + obase + mt * 16 + quad * 4) = pk;
            }
        }
    }

    // ---- V GEMM: C[pixel][o]; wave w -> channels w*64..w*64+63 ----
    {
        f32x4 vacc[4][4];
        #pragma unroll
        for (int mt = 0; mt < 4; mt++)
            #pragma unroll
            for (int nt = 0; nt < 4; nt++) vacc[mt][nt] = (f32x4){0.f, 0.f, 0.f, 0.f};

        #pragma unroll
        for (int kk = 0; kk < 8; kk++) {
            short8 af[4];
            #pragma unroll
            for (int mt = 0; mt < 4; mt++)   // A[m=pix][k=c] from LDS
                af[mt] = *(const short8*)&xs[mt * 16 + m16][kk * 32 + quad * 8];
            #pragma unroll
            for (int nt = 0; nt < 4; nt++) {
                short8 bf = *(const short8*)(wv + (size_t)(w * 64 + nt * 16 + m16) * C_ + kk * 32 + quad * 8);
                #pragma unroll
                for (int mt = 0; mt < 4; mt++)
                    vacc[mt][nt] = __builtin_amdgcn_mfma_f32_16x16x32_bf16(af[mt], bf, vacc[mt][nt], 0, 0, 0);
            }
        }
        #pragma unroll
        for (int nt = 0; nt < 4; nt++) {
            int c = w * 64 + nt * 16 + m16;
            float bvc = bv[c];
            #pragma unroll
            for (int mt = 0; mt < 4; mt++) {
                us4 pk;
                pk.x = f2b(vacc[mt][nt][0] + bvc);
                pk.y = f2b(vacc[mt][nt][1] + bvc);
                pk.z = f2b(vacc[mt][nt][2] + bvc);
                pk.w = f2b(vacc[mt][nt][3] + bvc);
                *(us4*)(vt + ((size_t)b * C_ + c) * N_ + n0 + mt * 16 + quad * 4) = pk;
            }
        }
    }
}

// grid B_*49*JS = 1568. XCD swizzle: b = bx&7. Wave w: queries t*64+w*16,
// all 256 channels (16 ct). S^T = K*Q^T -> exp in-register -> A-frag pa.
// V tile [256][32] double-buffered in LDS with the PV k-perm pre-applied:
//   global j-seg seg*8 -> pos p0=(seg&1)*16+(seg>>1)*4 and p0+8
// so B-frag = ONE ds_read_b128 at vs[buf][c][quad*8].
// Pipeline: V 2-deep (prA/prB), K 1-deep (krA/krB); raw s_barrier with
// lgkmcnt(0)-only fence -> global loads remain outstanding across steps.
__global__ __launch_bounds__(256, 2)
void attn_kernel(const ushort* __restrict__ qb, const ushort* __restrict__ kb,
                 const ushort* __restrict__ vt,
                 ushort* __restrict__ op, float* __restrict__ lp)
{
    __shared__ __align__(16) ushort vs[2][C_][VSP];  // 40960 B

    const int bx   = blockIdx.x;
    const int b    = bx & 7;            // XCD-local batch
    const int rem  = bx >> 3;           // 0..195
    const int t    = rem >> 2;          // 0..48
    const int js   = rem & 3;
    const int tid  = threadIdx.x;
    const int w    = tid >> 6;
    const int lane = tid & 63;
    const int m16  = lane & 15;
    const int quad = lane >> 4;
    const int i0   = t * 64 + w * 16;

    const int steps = (js == 0) ? 13 : 12;               // 13+12+12+12 = 49
    const int jbase = ((js == 0) ? 0 : (1 + 12 * js)) * JT;

    const ushort* vtb = vt + (size_t)b * C_ * N_;
    const ushort* kbb = kb + (size_t)b * N_ * CI_;

    // Q B-frags (n=i side), loaded once: B[k=o][n=i] = q[i][o]
    short8 qf[2];
    {
        const ushort* qbase = qb + ((size_t)b * N_ + i0 + m16) * CI_;
        qf[0] = *(const short8*)(qbase + quad * 8);
        qf[1] = *(const short8*)(qbase + 32 + quad * 8);
    }

    f32x4 O[16];
    #pragma unroll
    for (int ct = 0; ct < 16; ct++) O[ct] = (f32x4){0.f, 0.f, 0.f, 0.f};
    float lsum = 0.f;

    // staging: thread -> c row (4 thr/row), 16B global segment seg
    const int sc  = tid >> 2;
    const int seg = tid & 3;
    const int p0  = (seg & 1) * 16 + (seg >> 1) * 4;     // permuted dest base

    short8 prA[4], prB[4];        // V prefetch, 2-deep alternating sets
    short8 krA[4], krB[4];        // K prefetch, 1-deep alternating sets

    #define PREFETCH(PR, J0)                                                   \
        {                                                                      \
            _Pragma("unroll")                                                  \
            for (int p = 0; p < 4; p++)                                        \
                PR[p] = *(const short8*)(vtb + (size_t)(p * 64 + sc) * N_ + (J0) + seg * 8); \
        }
    #define COMMIT(PR, BUF)                                                    \
        {                                                                      \
            _Pragma("unroll")                                                  \
            for (int p = 0; p < 4; p++) {                                      \
                *(us4*)&vs[BUF][p * 64 + sc][p0]     = ((const us4*)&PR[p])[0]; \
                *(us4*)&vs[BUF][p * 64 + sc][p0 + 8] = ((const us4*)&PR[p])[1]; \
            }                                                                  \
        }
    #define KLOAD(J0, KR)                                                      \
        {                                                                      \
            _Pragma("unroll")                                                  \
            for (int h = 0; h < 2; h++) {                                      \
                const ushort* krow = kbb + (size_t)((J0) + h * 16 + m16) * CI_; \
                KR[2 * h]     = *(const short8*)(krow + quad * 8);             \
                KR[2 * h + 1] = *(const short8*)(krow + 32 + quad * 8);        \
            }                                                                  \
        }
    // lgkm-only barrier: commits visible to other waves, global loads stay
    // outstanding (no vmcnt drain). sched_barrier(0) pins the asm in place.
    #define BAR()                                                              \
        {                                                                      \
            __builtin_amdgcn_sched_barrier(0);                                 \
            asm volatile("s_waitcnt lgkmcnt(0)");                              \
            __builtin_amdgcn_sched_barrier(0);                                 \
            __builtin_amdgcn_s_barrier();                                      \
            __builtin_amdgcn_sched_barrier(0);                                 \
        }

    // prologue: V(0)->prA->buf0, V(1)->prB (in flight), K(0)->krA
    PREFETCH(prA, jbase)
    PREFETCH(prB, jbase + JT)
    KLOAD(jbase, krA)
    COMMIT(prA, 0)
    BAR()

    // one step: CUR = literal buffer parity. PRC holds V(st+1) (committed at
    // step end), PRN receives V(st+2). KRC holds K(st), KRN receives K(st+1).
    #define STEP(CUR, PRC, PRN, KRC, KRN, ST)                                  \
    {                                                                          \
        const int j0_ = jbase + (ST) * JT;                                     \
        const bool more1_ = (ST) + 1 < steps;                                  \
        if ((ST) + 2 < steps) PREFETCH(PRN, j0_ + 2 * JT)                      \
        if (more1_) KLOAD(j0_ + JT, KRN)                                       \
        /* ---- S^T = K Q^T, exp in-register -> A-frag pa ---- */              \
        short8 pa;                                                             \
        _Pragma("unroll")                                                      \
        for (int h = 0; h < 2; h++) {                                          \
            f32x4 T = (f32x4){0.f, 0.f, 0.f, 0.f};                             \
            T = __builtin_amdgcn_mfma_f32_16x16x32_bf16(KRC[2 * h],     qf[0], T, 0, 0, 0); \
            T = __builtin_amdgcn_mfma_f32_16x16x32_bf16(KRC[2 * h + 1], qf[1], T, 0, 0, 0); \
            _Pragma("unroll")                                                  \
            for (int r = 0; r < 4; r++) {                                      \
                float pv = __expf(T[r] - 12.0f);   /* static shift */          \
                lsum += pv;                                                    \
                pa[h * 4 + r] = (short)f2b(pv);                                \
            }                                                                  \
        }                                                                      \
        /* ---- PV: O[i][c] += P V over all 256 ch ---- */                     \
        __builtin_amdgcn_s_setprio(1);                                         \
        _Pragma("unroll")                                                      \
        for (int ct = 0; ct < 16; ct++) {                                      \
            short8 vf = *(const short8*)&vs[CUR][ct * 16 + m16][quad * 8];     \
            O[ct] = __builtin_amdgcn_mfma_f32_16x16x32_bf16(pa, vf, O[ct], 0, 0, 0); \
        }                                                                      \
        __builtin_amdgcn_s_setprio(0);                                         \
        if (more1_) {                                                          \
            COMMIT(PRC, (CUR) ^ 1)                                             \
            BAR()                                                              \
        }                                                                      \
    }

    int st = 0;
    for (; st + 2 <= steps; st += 2) {
        STEP(0, prB, prA, krA, krB, st)
        STEP(1, prA, prB, krB, krA, st + 1)
    }
    if (st < steps)                       // steps==13 tail (even parity)
        STEP(0, prB, prA, krA, krB, st)

    // ---- in-wave l reduction over quads; every wave owns unique 16 q ----
    {
        float v = lsum;
        v += __shfl_xor(v, 16);
        v += __shfl_xor(v, 32);
        if (lane < 16)
            __builtin_nontemporal_store(v, &lp[(size_t)(b * JS + js) * N_ + i0 + lane]);
    }

    // ---- store bf16 partial O (nontemporal: don't evict K/V from L2) ----
    ushort* opb = op + (size_t)(b * JS + js) * C_ * N_;
    #pragma unroll
    for (int ct = 0; ct < 16; ct++) {
        us4 pk;
        pk.x = f2b(O[ct][0]);
        pk.y = f2b(O[ct][1]);
        pk.z = f2b(O[ct][2]);
        pk.w = f2b(O[ct][3]);
        __builtin_nontemporal_store(pk,
            (us4*)(opb + (size_t)(ct * 16 + m16) * N_ + i0 + quad * 4));
    }
    #undef PREFETCH
    #undef COMMIT
    #undef KLOAD
    #undef BAR
    #undef STEP
}

// grid 6272: thread -> (b, c, 4 consecutive i). out = gamma*Σp/Σl + x
__global__ __launch_bounds__(256)
void reduce_kernel(const ushort* __restrict__ op, const float* __restrict__ lp,
                   const float* __restrict__ x, const float* __restrict__ gamma_p,
                   float* __restrict__ out)
{
    const int g  = blockIdx.x * 256 + threadIdx.x;   // B*C*N/4 total
    const int i4 = g % (N_ / 4);
    const int c  = (g / (N_ / 4)) % C_;
    const int b  = g / ((N_ / 4) * C_);
    const size_t io = (size_t)i4 * 4;
    const float g0 = gamma_p[0];

    f32x4 acc = (f32x4){0.f, 0.f, 0.f, 0.f};
    f32x4 lt  = (f32x4){0.f, 0.f, 0.f, 0.f};
    #pragma unroll
    for (int js = 0; js < JS; js++) {
        us4 a = *(const us4*)(op + ((size_t)(b * JS + js) * C_ + c) * N_ + io);
        f32x4   l = *(const f32x4*)(lp + (size_t)(b * JS + js) * N_ + io);
        acc[0] += b2f(a.x); acc[1] += b2f(a.y); acc[2] += b2f(a.z); acc[3] += b2f(a.w);
        lt += l;
    }

    const size_t xo = ((size_t)b * C_ + c) * N_ + io;
    f32x4 xv = *(const f32x4*)(x + xo);
    f32x4 ov;
    #pragma unroll
    for (int u = 0; u < 4; u++) ov[u] = acc[u] * (g0 / lt[u]) + xv[u];
    *(f32x4*)(out + xo) = ov;
}

extern "C" void kernel_launch(void* const* d_in, const int* in_sizes, int n_in,
                              void* d_out, int out_size, void* d_ws, size_t ws_size,
                              hipStream_t stream)
{
    const float* x  = (const float*)d_in[0];
    const float* Wq = (const float*)d_in[1];
    const float* bq = (const float*)d_in[2];
    const float* Wk = (const float*)d_in[3];
    const float* bk = (const float*)d_in[4];
    const float* Wv = (const float*)d_in[5];
    const float* bv = (const float*)d_in[6];
    const float* gm = (const float*)d_in[7];
    float* out = (float*)d_out;

    ushort* qb   = (ushort*)d_ws;                    // [B][N][CI]  3.2 MB
    ushort* kb   = qb + (size_t)B_ * N_ * CI_;       // [B][N][CI]  3.2 MB
    ushort* vt   = kb + (size_t)B_ * N_ * CI_;       // [B][C][N]  12.8 MB
    ushort* xT   = vt + (size_t)B_ * C_ * N_;        // [B][N][C]  12.8 MB
    ushort* wqk  = xT + (size_t)B_ * N_ * C_;        // [128][256] 64 KB
    ushort* wv   = wqk + 128 * C_;                   // [256][256] 128 KB
    ushort* op   = wv + 256 * C_;                    // [B][JS][C][N] bf16 51.4 MB
    float*  lpf  = (float*)(op + (size_t)B_ * JS * C_ * N_);  // [B][JS][N] 401 KB

    hipLaunchKernelGGL(pre_kernel, dim3(B_ * 196 + 256), dim3(256), 0, stream,
                       x, Wq, Wk, Wv, xT, wqk, wv);
    hipLaunchKernelGGL(proj_kernel, dim3(B_ * 49), dim3(256), 0, stream,
                       xT, wqk, wv, bq, bk, bv, qb, kb, vt);
    hipLaunchKernelGGL(attn_kernel, dim3(B_ * 49 * JS), dim3(256), 0, stream,
                       qb, kb, vt, op, lpf);
    hipLaunchKernelGGL(reduce_kernel, dim3(B_ * C_ * (N_ / 4) / 256), dim3(256), 0, stream,
                       op, lpf, x, gm, out);
}

// Round 5
// 204.267 us; speedup vs baseline: 1.0296x; 1.0296x over previous
//
#include <hip/hip_runtime.h>

// PixelPropagationModule  out = gamma * (softmax(qk^T) @ v^T)^T + x
// B=8, C=256, CI=64, N=3136 (56x56), fp32 in/out.
// R11: STRAIGHT-LINE pinned pipeline. R10 NaN post-mortem: manual vmcnt
//      counting is only sound if (a) no scratch spills (scratch ops bump
//      vmcnt) and (b) no allocator copies of in-flight asm-defined regs at
//      control-flow joins. R10 violated both (VGPR cap 170 ~= live set;
//      runtime-trip loop + parity branches). Fix:
//      - FULL UNROLL: branch once on js==0 into RUN(13)/RUN(12); #pragma
//        unroll with literal trip count; all pipeline conditions constant-
//        fold; pr[2][4]/kr[2][4] indexed by constants -> pure registers;
//        no joins -> no copies.
//      - NO VGPR CAP: plain launch_bounds(256); ~170 live < 256 budget ->
//        no spills. Volatile asm keeps mutual program order -> exact counts.
//      - "memory" clobber on all waitcnt asm.
//      Invariant: entering step st, outstanding = {V(st+1)x4, K(st)x4};
//      full step issues V(st+2)+K(st+1) then vmcnt(8); epilogue vmcnt(4)/(0).
//      Structure = R9b: wave = 16q x 256ch, 64q blocks, grid B*49*JS,
//      XCD swizzle b=bx&7, double-buffered permuted V LDS, one lgkm-only
//      barrier/step, nt op/lp stores. pre/proj/reduce unchanged.

constexpr int B_  = 8;
constexpr int C_  = 256;
constexpr int CI_ = 64;
constexpr int N_  = 3136;
constexpr int JS  = 4;        // attn j-split
constexpr int JT  = 32;       // attn j per step
constexpr int VSP = 40;       // V LDS row pitch (ushorts) = 80 B
constexpr int PN  = 64;       // proj pixel tile
constexpr int XSP = C_ + 8;   // proj LDS row pitch

typedef __attribute__((ext_vector_type(8))) short short8;   // 8 bf16 (4 VGPR)
typedef __attribute__((ext_vector_type(4))) float f32x4;
typedef __attribute__((ext_vector_type(4))) ushort us4;     // clang vec (nt-store ok)

static __device__ inline ushort f2b(float f) {               // fp32 -> bf16 (RNE)
    unsigned u = __float_as_uint(f);
    return (ushort)((u + 0x7fffu + ((u >> 16) & 1u)) >> 16);
}
static __device__ inline float b2f(ushort h) {
    return __uint_as_float(((unsigned)h) << 16);
}

// blocks [0, B_*196): x[B][C][N] f32 -> xT[B][N][C] bf16 (LDS transpose)
// blocks [B_*196, +256): Wq/Wk -> wqk[128][256], Wv -> wv[256][256] bf16
__global__ __launch_bounds__(256)
void pre_kernel(const float* __restrict__ x,
                const float* __restrict__ Wq, const float* __restrict__ Wk,
                const float* __restrict__ Wv,
                ushort* __restrict__ xT, ushort* __restrict__ wqk, ushort* __restrict__ wv)
{
    __shared__ float ts[64][65];
    const int bx  = blockIdx.x;
    const int tid = threadIdx.x;

    if (bx >= B_ * 196) {                            // weight convert
        int i = (bx - B_ * 196) * 256 + tid;
        if (i < 16384)      wqk[i] = f2b(Wq[i]);
        else if (i < 32768) wqk[i] = f2b(Wk[i - 16384]);
        wv[i] = f2b(Wv[i]);
        return;
    }

    const int b  = bx / 196;
    const int rm = bx % 196;
    const int n0 = (rm >> 2) * 64;
    const int c0 = (rm & 3) * 64;

    const float* src = x + ((size_t)b * C_ + c0) * N_ + n0;
    #pragma unroll
    for (int rep = 0; rep < 16; rep++) {             // 4096 floats in
        int e = rep * 256 + tid;
        int c = e >> 6, n = e & 63;
        ts[c][n] = src[(size_t)c * N_ + n];
    }
    __syncthreads();
    ushort* dst = xT + ((size_t)b * N_ + n0) * C_ + c0;
    #pragma unroll
    for (int rep = 0; rep < 8; rep++) {              // 2048 ushort2 out
        int e = rep * 256 + tid;
        int n = e >> 5, c2 = (e & 31) * 2;
        ushort2 o;
        o.x = f2b(ts[c2][n]);
        o.y = f2b(ts[c2 + 1][n]);
        *(ushort2*)(dst + (size_t)n * C_ + c2) = o;
    }
}

__global__ __launch_bounds__(256)
void proj_kernel(const ushort* __restrict__ xT, const ushort* __restrict__ wqk,
                 const ushort* __restrict__ wv,
                 const float* __restrict__ bq, const float* __restrict__ bk,
                 const float* __restrict__ bv,
                 ushort* __restrict__ qb, ushort* __restrict__ kb, ushort* __restrict__ vt)
{
    __shared__ ushort xs[PN][XSP];        // 33792 B
    const int b   = blockIdx.x / 49;
    const int n0  = (blockIdx.x % 49) * PN;
    const int tid = threadIdx.x;
    const int w    = tid >> 6;
    const int lane = tid & 63;
    const int m16  = lane & 15;
    const int quad = lane >> 4;

    // stage xT tile [64 pixels][256 c] bf16
    {
        const ushort* src = xT + ((size_t)b * N_ + n0) * C_;
        #pragma unroll
        for (int rep = 0; rep < 8; rep++) {
            int e = rep * 256 + tid;
            int row = e >> 5, ch = (e & 31) * 8;
            *(short8*)&xs[row][ch] = *(const short8*)(src + (size_t)row * C_ + ch);
        }
    }
    __syncthreads();

    // ---- QK GEMM: C[o][pixel]; waves 0,1 -> Q halves, 2,3 -> K halves ----
    {
        f32x4 acc[2][4];
        #pragma unroll
        for (int mt = 0; mt < 2; mt++)
            #pragma unroll
            for (int nt = 0; nt < 4; nt++) acc[mt][nt] = (f32x4){0.f, 0.f, 0.f, 0.f};

        #pragma unroll
        for (int kk = 0; kk < 8; kk++) {
            short8 af[2];
            #pragma unroll
            for (int mt = 0; mt < 2; mt++)   // A[m=o][k=c] = wqk row (L2-hot)
                af[mt] = *(const short8*)(wqk + (size_t)(w * 32 + mt * 16 + m16) * C_ + kk * 32 + quad * 8);
            #pragma unroll
            for (int nt = 0; nt < 4; nt++) {
                short8 bf = *(const short8*)&xs[nt * 16 + m16][kk * 32 + quad * 8];  // B[k=c][n=pix]
                #pragma unroll
                for (int mt = 0; mt < 2; mt++)
                    acc[mt][nt] = __builtin_amdgcn_mfma_f32_16x16x32_bf16(af[mt], bf, acc[mt][nt], 0, 0, 0);
            }
        }
        const float* bias = (w < 2) ? bq : bk;
        ushort* dst = (w < 2) ? qb : kb;
        const int obase = (w & 1) * 32;
        #pragma unroll
        for (int mt = 0; mt < 2; mt++) {
            f32x4 bs = *(const f32x4*)(bias + obase + mt * 16 + quad * 4);
            #pragma unroll
            for (int nt = 0; nt < 4; nt++) {
                us4 pk;
                pk.x = f2b(acc[mt][nt][0] + bs[0]);
                pk.y = f2b(acc[mt][nt][1] + bs[1]);
                pk.z = f2b(acc[mt][nt][2] + bs[2]);
                pk.w = f2b(acc[mt][nt][3] + bs[3]);
                *(us4*)(dst + ((size_t)b * N_ + n0 + nt * 16 + m16) * CI_ + obase + mt * 16 + quad * 4) = pk;
            }
        }
    }

    // ---- V GEMM: C[pixel][o]; wave w -> channels w*64..w*64+63 ----
    {
        f32x4 vacc[4][4];
        #pragma unroll
        for (int mt = 0; mt < 4; mt++)
            #pragma unroll
            for (int nt = 0; nt < 4; nt++) vacc[mt][nt] = (f32x4){0.f, 0.f, 0.f, 0.f};

        #pragma unroll
        for (int kk = 0; kk < 8; kk++) {
            short8 af[4];
            #pragma unroll
            for (int mt = 0; mt < 4; mt++)   // A[m=pix][k=c] from LDS
                af[mt] = *(const short8*)&xs[mt * 16 + m16][kk * 32 + quad * 8];
            #pragma unroll
            for (int nt = 0; nt < 4; nt++) {
                short8 bf = *(const short8*)(wv + (size_t)(w * 64 + nt * 16 + m16) * C_ + kk * 32 + quad * 8);
                #pragma unroll
                for (int mt = 0; mt < 4; mt++)
                    vacc[mt][nt] = __builtin_amdgcn_mfma_f32_16x16x32_bf16(af[mt], bf, vacc[mt][nt], 0, 0, 0);
            }
        }
        #pragma unroll
        for (int nt = 0; nt < 4; nt++) {
            int c = w * 64 + nt * 16 + m16;
            float bvc = bv[c];
            #pragma unroll
            for (int mt = 0; mt < 4; mt++) {
                us4 pk;
                pk.x = f2b(vacc[mt][nt][0] + bvc);
                pk.y = f2b(vacc[mt][nt][1] + bvc);
                pk.z = f2b(vacc[mt][nt][2] + bvc);
                pk.w = f2b(vacc[mt][nt][3] + bvc);
                *(us4*)(vt + ((size_t)b * C_ + c) * N_ + n0 + mt * 16 + quad * 4) = pk;
            }
        }
    }
}

// grid B_*49*JS = 1568. XCD swizzle: b = bx&7. Wave w: queries t*64+w*16,
// all 256 channels (16 ct). S^T = K*Q^T -> exp in-register -> A-frag pa.
// V tile [256][32] double-buffered in LDS with the PV k-perm pre-applied.
// ALL V/K loads via volatile inline-asm global_load_dwordx4 (order-pinned,
// cannot sink) + manual vmcnt. Fully unrolled static schedule -> no PHI
// copies; no VGPR cap -> no scratch (scratch would corrupt vmcnt counts).
__global__ __launch_bounds__(256)
void attn_kernel(const ushort* __restrict__ qb, const ushort* __restrict__ kb,
                 const ushort* __restrict__ vt,
                 ushort* __restrict__ op, float* __restrict__ lp)
{
    __shared__ __align__(16) ushort vs[2][C_][VSP];  // 40960 B

    const int bx   = blockIdx.x;
    const int b    = bx & 7;            // XCD-local batch
    const int rem  = bx >> 3;           // 0..195
    const int t    = rem >> 2;          // 0..48
    const int js   = rem & 3;
    const int tid  = threadIdx.x;
    const int w    = tid >> 6;
    const int lane = tid & 63;
    const int m16  = lane & 15;
    const int quad = lane >> 4;
    const int i0   = t * 64 + w * 16;

    const int jbase = ((js == 0) ? 0 : (1 + 12 * js)) * JT;  // steps 13/12

    const ushort* vtb = vt + (size_t)b * C_ * N_;
    const ushort* kbb = kb + (size_t)b * N_ * CI_;

    f32x4 O[16];
    #pragma unroll
    for (int ct = 0; ct < 16; ct++) O[ct] = (f32x4){0.f, 0.f, 0.f, 0.f};
    float lsum = 0.f;

    // staging: thread -> c row (4 thr/row), 16B global segment seg
    const int sc  = tid >> 2;
    const int seg = tid & 3;
    const int p0  = (seg & 1) * 16 + (seg >> 1) * 4;     // permuted dest base

    const ushort* vbase[4];
    #pragma unroll
    for (int p = 0; p < 4; p++)
        vbase[p] = vtb + (size_t)(p * 64 + sc) * N_ + seg * 8;

    short8 qf[2];                 // Q B-frags (loaded once, drained)
    short8 pr[2][4];              // V prefetch, 2-deep (parity-indexed, static)
    short8 kr[2][4];              // K prefetch, 1-deep (parity-indexed, static)

    #define GLOAD(DST, ADDR)                                                   \
        asm volatile("global_load_dwordx4 %0, %1, off"                         \
                     : "=v"(DST) : "v"(ADDR));
    #define GPREFETCH(PR, J0)                                                  \
        {                                                                      \
            _Pragma("unroll")                                                  \
            for (int p = 0; p < 4; p++) {                                      \
                const ushort* a_ = vbase[p] + (J0);                            \
                GLOAD(PR[p], a_)                                               \
            }                                                                  \
        }
    #define GKLOAD(J0, KR)                                                     \
        {                                                                      \
            _Pragma("unroll")                                                  \
            for (int h = 0; h < 2; h++) {                                      \
                const ushort* krow = kbb + (size_t)((J0) + h * 16 + m16) * CI_; \
                const ushort* a0_ = krow + quad * 8;                           \
                const ushort* a1_ = krow + 32 + quad * 8;                      \
                GLOAD(KR[2 * h], a0_)                                          \
                GLOAD(KR[2 * h + 1], a1_)                                      \
            }                                                                  \
        }
    #define COMMIT(PR, BUF)                                                    \
        {                                                                      \
            _Pragma("unroll")                                                  \
            for (int p = 0; p < 4; p++) {                                      \
                *(us4*)&vs[BUF][p * 64 + sc][p0]     = ((const us4*)&PR[p])[0]; \
                *(us4*)&vs[BUF][p * 64 + sc][p0 + 8] = ((const us4*)&PR[p])[1]; \
            }                                                                  \
        }
    #define VWAIT(N)                                                           \
        {                                                                      \
            asm volatile("s_waitcnt vmcnt(" #N ")" ::: "memory");              \
            __builtin_amdgcn_sched_barrier(0);                                 \
        }
    // lgkm-only barrier: commits visible, global loads stay outstanding.
    #define BAR()                                                              \
        {                                                                      \
            __builtin_amdgcn_sched_barrier(0);                                 \
            asm volatile("s_waitcnt lgkmcnt(0)" ::: "memory");                 \
            __builtin_amdgcn_sched_barrier(0);                                 \
            __builtin_amdgcn_s_barrier();                                      \
            __builtin_amdgcn_sched_barrier(0);                                 \
        }
    // QK (S^T = K Q^T) -> exp -> pa ; PV over all 256 ch from vs[CUR]
    #define COMPUTE(CUR, KRC)                                                  \
        {                                                                      \
            short8 pa;                                                         \
            _Pragma("unroll")                                                  \
            for (int h = 0; h < 2; h++) {                                      \
                f32x4 T = (f32x4){0.f, 0.f, 0.f, 0.f};                         \
                T = __builtin_amdgcn_mfma_f32_16x16x32_bf16(KRC[2 * h],     qf[0], T, 0, 0, 0); \
                T = __builtin_amdgcn_mfma_f32_16x16x32_bf16(KRC[2 * h + 1], qf[1], T, 0, 0, 0); \
                _Pragma("unroll")                                              \
                for (int r = 0; r < 4; r++) {                                  \
                    float pv = __expf(T[r] - 12.0f);   /* static shift */      \
                    lsum += pv;                                                \
                    pa[h * 4 + r] = (short)f2b(pv);                            \
                }                                                              \
            }                                                                  \
            __builtin_amdgcn_s_setprio(1);                                     \
            _Pragma("unroll")                                                  \
            for (int ct = 0; ct < 16; ct++) {                                  \
                short8 vf = *(const short8*)&vs[CUR][ct * 16 + m16][quad * 8]; \
                O[ct] = __builtin_amdgcn_mfma_f32_16x16x32_bf16(pa, vf, O[ct], 0, 0, 0); \
            }                                                                  \
            __builtin_amdgcn_s_setprio(0);                                     \
        }

    // ---- prologue: qf (drained), then V(0),V(1),K(0) pinned in flight ----
    {
        const ushort* qbase = qb + ((size_t)b * N_ + i0 + m16) * CI_;
        const ushort* qa0 = qbase + quad * 8;
        const ushort* qa1 = qbase + 32 + quad * 8;
        GLOAD(qf[0], qa0)
        GLOAD(qf[1], qa1)
        VWAIT(0)
    }
    GPREFETCH(pr[0], jbase)
    GPREFETCH(pr[1], jbase + JT)
    GKLOAD(jbase, kr[0])
    VWAIT(8)                               // retire pr[0] (oldest 4 of 12)
    COMMIT(pr[0], 0)
    BAR()
    // entering step 0: outstanding = {V(1) in pr[1], K(0) in kr[0]} = 8

    // Fully-unrolled schedule; all conditions constant-fold per iteration.
    // Full step (st+2<S):  issue V(st+2)->pr[cur], K(st+1)->kr[cur^1];
    //   16 outstanding -> vmcnt(8) retires V(st+1)+K(st).
    // Epi1 (st==S-2): issue K only; 12 outstanding -> vmcnt(4).
    // Epi2 (st==S-1): nothing issued -> vmcnt(0).
    #define RUN(STEPS_)                                                        \
        _Pragma("unroll")                                                      \
        for (int st = 0; st < (STEPS_); ++st) {                                \
            const int cur = st & 1;                                            \
            const int j0_ = jbase + st * JT;                                   \
            if (st + 2 < (STEPS_)) GPREFETCH(pr[cur], j0_ + 2 * JT)            \
            if (st + 1 < (STEPS_)) GKLOAD(j0_ + JT, kr[cur ^ 1])               \
            if (st + 2 < (STEPS_)) { VWAIT(8) }                                \
            else if (st + 1 < (STEPS_)) { VWAIT(4) }                           \
            else { VWAIT(0) }                                                  \
            COMPUTE(cur, kr[cur])                                              \
            if (st + 1 < (STEPS_)) {                                           \
                COMMIT(pr[cur ^ 1], cur ^ 1)                                   \
                BAR()                                                          \
            }                                                                  \
        }

    if (js == 0) { RUN(13) } else { RUN(12) }
    #undef RUN

    // ---- in-wave l reduction over quads; every wave owns unique 16 q ----
    {
        float v = lsum;
        v += __shfl_xor(v, 16);
        v += __shfl_xor(v, 32);
        if (lane < 16)
            __builtin_nontemporal_store(v, &lp[(size_t)(b * JS + js) * N_ + i0 + lane]);
    }

    // ---- store bf16 partial O (nontemporal: don't evict K/V from L2) ----
    ushort* opb = op + (size_t)(b * JS + js) * C_ * N_;
    #pragma unroll
    for (int ct = 0; ct < 16; ct++) {
        us4 pk;
        pk.x = f2b(O[ct][0]);
        pk.y = f2b(O[ct][1]);
        pk.z = f2b(O[ct][2]);
        pk.w = f2b(O[ct][3]);
        __builtin_nontemporal_store(pk,
            (us4*)(opb + (size_t)(ct * 16 + m16) * N_ + i0 + quad * 4));
    }
    #undef GLOAD
    #undef GPREFETCH
    #undef GKLOAD
    #undef COMMIT
    #undef VWAIT
    #undef BAR
    #undef COMPUTE
}

// grid 6272: thread -> (b, c, 4 consecutive i). out = gamma*Σp/Σl + x
__global__ __launch_bounds__(256)
void reduce_kernel(const ushort* __restrict__ op, const float* __restrict__ lp,
                   const float* __restrict__ x, const float* __restrict__ gamma_p,
                   float* __restrict__ out)
{
    const int g  = blockIdx.x * 256 + threadIdx.x;   // B*C*N/4 total
    const int i4 = g % (N_ / 4);
    const int c  = (g / (N_ / 4)) % C_;
    const int b  = g / ((N_ / 4) * C_);
    const size_t io = (size_t)i4 * 4;
    const float g0 = gamma_p[0];

    f32x4 acc = (f32x4){0.f, 0.f, 0.f, 0.f};
    f32x4 lt  = (f32x4){0.f, 0.f, 0.f, 0.f};
    #pragma unroll
    for (int js = 0; js < JS; js++) {
        us4 a = *(const us4*)(op + ((size_t)(b * JS + js) * C_ + c) * N_ + io);
        f32x4   l = *(const f32x4*)(lp + (size_t)(b * JS + js) * N_ + io);
        acc[0] += b2f(a.x); acc[1] += b2f(a.y); acc[2] += b2f(a.z); acc[3] += b2f(a.w);
        lt += l;
    }

    const size_t xo = ((size_t)b * C_ + c) * N_ + io;
    f32x4 xv = *(const f32x4*)(x + xo);
    f32x4 ov;
    #pragma unroll
    for (int u = 0; u < 4; u++) ov[u] = acc[u] * (g0 / lt[u]) + xv[u];
    *(f32x4*)(out + xo) = ov;
}

extern "C" void kernel_launch(void* const* d_in, const int* in_sizes, int n_in,
                              void* d_out, int out_size, void* d_ws, size_t ws_size,
                              hipStream_t stream)
{
    const float* x  = (const float*)d_in[0];
    const float* Wq = (const float*)d_in[1];
    const float* bq = (const float*)d_in[2];
    const float* Wk = (const float*)d_in[3];
    const float* bk = (const float*)d_in[4];
    const float* Wv = (const float*)d_in[5];
    const float* bv = (const float*)d_in[6];
    const float* gm = (const float*)d_in[7];
    float* out = (float*)d_out;

    ushort* qb   = (ushort*)d_ws;                    // [B][N][CI]  3.2 MB
    ushort* kb   = qb + (size_t)B_ * N_ * CI_;       // [B][N][CI]  3.2 MB
    ushort* vt   = kb + (size_t)B_ * N_ * CI_;       // [B][C][N]  12.8 MB
    ushort* xT   = vt + (size_t)B_ * C_ * N_;        // [B][N][C]  12.8 MB
    ushort* wqk  = xT + (size_t)B_ * N_ * C_;        // [128][256] 64 KB
    ushort* wv   = wqk + 128 * C_;                   // [256][256] 128 KB
    ushort* op   = wv + 256 * C_;                    // [B][JS][C][N] bf16 51.4 MB
    float*  lpf  = (float*)(op + (size_t)B_ * JS * C_ * N_);  // [B][JS][N] 401 KB

    hipLaunchKernelGGL(pre_kernel, dim3(B_ * 196 + 256), dim3(256), 0, stream,
                       x, Wq, Wk, Wv, xT, wqk, wv);
    hipLaunchKernelGGL(proj_kernel, dim3(B_ * 49), dim3(256), 0, stream,
                       xT, wqk, wv, bq, bk, bv, qb, kb, vt);
    hipLaunchKernelGGL(attn_kernel, dim3(B_ * 49 * JS), dim3(256), 0, stream,
                       qb, kb, vt, op, lpf);
    hipLaunchKernelGGL(reduce_kernel, dim3(B_ * C_ * (N_ / 4) / 256), dim3(256), 0, stream,
                       op, lpf, x, gm, out);
}

// Round 6
// 201.276 us; speedup vs baseline: 1.0449x; 1.0149x over previous
//
#include <hip/hip_runtime.h>

// PixelPropagationModule  out = gamma * (softmax(qk^T) @ v^T)^T + x
// B=8, C=256, CI=64, N=3136 (56x56), fp32 in/out.
// R12: 32q/wave via dual A-tiles (B-frag reuse x2). R11 post-mortem: kernel
//      is aggregate-ISSUE-bound (per-step wall ~3470cy vs ~550cy/wave issue;
//      latency pipeline depth changed nothing). Dominant per-query cost =
//      per-wave re-read of the full 16KB V tile per step for only 16 q.
//      Fix: wave owns 32 queries (two 16-row A-tiles pa0/pa1); every vf
//      ds_read_b128 feeds TWO PV MFMAs -> per-query LDS reads, commits and
//      barrier overhead halved. Same 16x16x32 MFMA, same V k-permutation.
//      Block = 4 waves x 32q = 128q -> grid B*25*JS = 800; tail t=24 has 2
//      masked waves (loads clamped, stores skipped; they still hit barriers).
//      Pipeline: 1-deep V (pr[4]) + 1-deep K (kr[2][4]), pinned asm loads,
//      manual vmcnt 8/4/0, fully unrolled RUN(13)/RUN(12), lgkm-only BAR.
//      pre/proj/reduce unchanged.

constexpr int B_  = 8;
constexpr int C_  = 256;
constexpr int CI_ = 64;
constexpr int N_  = 3136;
constexpr int JS  = 4;        // attn j-split
constexpr int JT  = 32;       // attn j per step
constexpr int VSP = 40;       // V LDS row pitch (ushorts) = 80 B
constexpr int PN  = 64;       // proj pixel tile
constexpr int XSP = C_ + 8;   // proj LDS row pitch

typedef __attribute__((ext_vector_type(8))) short short8;   // 8 bf16 (4 VGPR)
typedef __attribute__((ext_vector_type(4))) float f32x4;
typedef __attribute__((ext_vector_type(4))) ushort us4;     // clang vec (nt-store ok)

static __device__ inline ushort f2b(float f) {               // fp32 -> bf16 (RNE)
    unsigned u = __float_as_uint(f);
    return (ushort)((u + 0x7fffu + ((u >> 16) & 1u)) >> 16);
}
static __device__ inline float b2f(ushort h) {
    return __uint_as_float(((unsigned)h) << 16);
}

// blocks [0, B_*196): x[B][C][N] f32 -> xT[B][N][C] bf16 (LDS transpose)
// blocks [B_*196, +256): Wq/Wk -> wqk[128][256], Wv -> wv[256][256] bf16
__global__ __launch_bounds__(256)
void pre_kernel(const float* __restrict__ x,
                const float* __restrict__ Wq, const float* __restrict__ Wk,
                const float* __restrict__ Wv,
                ushort* __restrict__ xT, ushort* __restrict__ wqk, ushort* __restrict__ wv)
{
    __shared__ float ts[64][65];
    const int bx  = blockIdx.x;
    const int tid = threadIdx.x;

    if (bx >= B_ * 196) {                            // weight convert
        int i = (bx - B_ * 196) * 256 + tid;
        if (i < 16384)      wqk[i] = f2b(Wq[i]);
        else if (i < 32768) wqk[i] = f2b(Wk[i - 16384]);
        wv[i] = f2b(Wv[i]);
        return;
    }

    const int b  = bx / 196;
    const int rm = bx % 196;
    const int n0 = (rm >> 2) * 64;
    const int c0 = (rm & 3) * 64;

    const float* src = x + ((size_t)b * C_ + c0) * N_ + n0;
    #pragma unroll
    for (int rep = 0; rep < 16; rep++) {             // 4096 floats in
        int e = rep * 256 + tid;
        int c = e >> 6, n = e & 63;
        ts[c][n] = src[(size_t)c * N_ + n];
    }
    __syncthreads();
    ushort* dst = xT + ((size_t)b * N_ + n0) * C_ + c0;
    #pragma unroll
    for (int rep = 0; rep < 8; rep++) {              // 2048 ushort2 out
        int e = rep * 256 + tid;
        int n = e >> 5, c2 = (e & 31) * 2;
        ushort2 o;
        o.x = f2b(ts[c2][n]);
        o.y = f2b(ts[c2 + 1][n]);
        *(ushort2*)(dst + (size_t)n * C_ + c2) = o;
    }
}

__global__ __launch_bounds__(256)
void proj_kernel(const ushort* __restrict__ xT, const ushort* __restrict__ wqk,
                 const ushort* __restrict__ wv,
                 const float* __restrict__ bq, const float* __restrict__ bk,
                 const float* __restrict__ bv,
                 ushort* __restrict__ qb, ushort* __restrict__ kb, ushort* __restrict__ vt)
{
    __shared__ ushort xs[PN][XSP];        // 33792 B
    const int b   = blockIdx.x / 49;
    const int n0  = (blockIdx.x % 49) * PN;
    const int tid = threadIdx.x;
    const int w    = tid >> 6;
    const int lane = tid & 63;
    const int m16  = lane & 15;
    const int quad = lane >> 4;

    // stage xT tile [64 pixels][256 c] bf16
    {
        const ushort* src = xT + ((size_t)b * N_ + n0) * C_;
        #pragma unroll
        for (int rep = 0; rep < 8; rep++) {
            int e = rep * 256 + tid;
            int row = e >> 5, ch = (e & 31) * 8;
            *(short8*)&xs[row][ch] = *(const short8*)(src + (size_t)row * C_ + ch);
        }
    }
    __syncthreads();

    // ---- QK GEMM: C[o][pixel]; waves 0,1 -> Q halves, 2,3 -> K halves ----
    {
        f32x4 acc[2][4];
        #pragma unroll
        for (int mt = 0; mt < 2; mt++)
            #pragma unroll
            for (int nt = 0; nt < 4; nt++) acc[mt][nt] = (f32x4){0.f, 0.f, 0.f, 0.f};

        #pragma unroll
        for (int kk = 0; kk < 8; kk++) {
            short8 af[2];
            #pragma unroll
            for (int mt = 0; mt < 2; mt++)   // A[m=o][k=c] = wqk row (L2-hot)
                af[mt] = *(const short8*)(wqk + (size_t)(w * 32 + mt * 16 + m16) * C_ + kk * 32 + quad * 8);
            #pragma unroll
            for (int nt = 0; nt < 4; nt++) {
                short8 bf = *(const short8*)&xs[nt * 16 + m16][kk * 32 + quad * 8];  // B[k=c][n=pix]
                #pragma unroll
                for (int mt = 0; mt < 2; mt++)
                    acc[mt][nt] = __builtin_amdgcn_mfma_f32_16x16x32_bf16(af[mt], bf, acc[mt][nt], 0, 0, 0);
            }
        }
        const float* bias = (w < 2) ? bq : bk;
        ushort* dst = (w < 2) ? qb : kb;
        const int obase = (w & 1) * 32;
        #pragma unroll
        for (int mt = 0; mt < 2; mt++) {
            f32x4 bs = *(const f32x4*)(bias + obase + mt * 16 + quad * 4);
            #pragma unroll
            for (int nt = 0; nt < 4; nt++) {
                us4 pk;
                pk.x = f2b(acc[mt][nt][0] + bs[0]);
                pk.y = f2b(acc[mt][nt][1] + bs[1]);
                pk.z = f2b(acc[mt][nt][2] + bs[2]);
                pk.w = f2b(acc[mt][nt][3] + bs[3]);
                *(us4*)(dst + ((size_t)b * N_ + n0 + nt * 16 + m16) * CI_ + obase + mt * 16 + quad * 4) = pk;
            }
        }
    }

    // ---- V GEMM: C[pixel][o]; wave w -> channels w*64..w*64+63 ----
    {
        f32x4 vacc[4][4];
        #pragma unroll
        for (int mt = 0; mt < 4; mt++)
            #pragma unroll
            for (int nt = 0; nt < 4; nt++) vacc[mt][nt] = (f32x4){0.f, 0.f, 0.f, 0.f};

        #pragma unroll
        for (int kk = 0; kk < 8; kk++) {
            short8 af[4];
            #pragma unroll
            for (int mt = 0; mt < 4; mt++)   // A[m=pix][k=c] from LDS
                af[mt] = *(const short8*)&xs[mt * 16 + m16][kk * 32 + quad * 8];
            #pragma unroll
            for (int nt = 0; nt < 4; nt++) {
                short8 bf = *(const short8*)(wv + (size_t)(w * 64 + nt * 16 + m16) * C_ + kk * 32 + quad * 8);
                #pragma unroll
                for (int mt = 0; mt < 4; mt++)
                    vacc[mt][nt] = __builtin_amdgcn_mfma_f32_16x16x32_bf16(af[mt], bf, vacc[mt][nt], 0, 0, 0);
            }
        }
        #pragma unroll
        for (int nt = 0; nt < 4; nt++) {
            int c = w * 64 + nt * 16 + m16;
            float bvc = bv[c];
            #pragma unroll
            for (int mt = 0; mt < 4; mt++) {
                us4 pk;
                pk.x = f2b(vacc[mt][nt][0] + bvc);
                pk.y = f2b(vacc[mt][nt][1] + bvc);
                pk.z = f2b(vacc[mt][nt][2] + bvc);
                pk.w = f2b(vacc[mt][nt][3] + bvc);
                *(us4*)(vt + ((size_t)b * C_ + c) * N_ + n0 + mt * 16 + quad * 4) = pk;
            }
        }
    }
}

// grid B_*25*JS = 800. XCD swizzle: b = bx&7. Block = 4 waves x 32q = 128q.
// Wave w: queries i0 = t*128 + w*32 as two 16-row groups (pa0/pa1), all 256
// channels. Every vf ds_read_b128 feeds TWO PV MFMAs (O0,O1). Tail t=24:
// waves with i0+32 > N_ clamp loads to N_-32 and skip stores (still barrier).
// V tile double-buffered in LDS with PV k-perm pre-applied. Pinned asm
// loads + manual vmcnt: full step issues V(st+1)x4 + K(st+1)x4 on top of
// K(st)x4 -> vmcnt(8) retires K(st); vmcnt(4) after compute retires V(st+1);
// last step vmcnt(0). One lgkm-only barrier per step.
__global__ __launch_bounds__(256)
void attn_kernel(const ushort* __restrict__ qb, const ushort* __restrict__ kb,
                 const ushort* __restrict__ vt,
                 ushort* __restrict__ op, float* __restrict__ lp)
{
    __shared__ __align__(16) ushort vs[2][C_][VSP];  // 40960 B

    const int bx   = blockIdx.x;
    const int b    = bx & 7;            // XCD-local batch
    const int rem  = bx >> 3;           // 0..99
    const int t    = rem >> 2;          // 0..24
    const int js   = rem & 3;
    const int tid  = threadIdx.x;
    const int w    = tid >> 6;
    const int lane = tid & 63;
    const int m16  = lane & 15;
    const int quad = lane >> 4;
    const int i0   = t * 128 + w * 32;
    const bool iv  = (i0 + 32 <= N_);                // valid-store wave?
    const int iq   = iv ? i0 : (N_ - 32);            // clamped load base

    const int jbase = ((js == 0) ? 0 : (1 + 12 * js)) * JT;  // steps 13/12

    const ushort* vtb = vt + (size_t)b * C_ * N_;
    const ushort* kbb = kb + (size_t)b * N_ * CI_;

    f32x4 O0[16], O1[16];
    #pragma unroll
    for (int ct = 0; ct < 16; ct++) {
        O0[ct] = (f32x4){0.f, 0.f, 0.f, 0.f};
        O1[ct] = (f32x4){0.f, 0.f, 0.f, 0.f};
    }
    float lsum0 = 0.f, lsum1 = 0.f;

    // staging: thread -> c row (4 thr/row), 16B global segment seg
    const int sc  = tid >> 2;
    const int seg = tid & 3;
    const int p0  = (seg & 1) * 16 + (seg >> 1) * 4;     // permuted dest base

    const ushort* vbase[4];
    #pragma unroll
    for (int p = 0; p < 4; p++)
        vbase[p] = vtb + (size_t)(p * 64 + sc) * N_ + seg * 8;

    short8 qf[4];                 // Q B-frags: [g*2+half], loaded once
    short8 pr[4];                 // V prefetch, 1-deep
    short8 kr[2][4];              // K prefetch, 1-deep alternating sets

    #define GLOAD(DST, ADDR)                                                   \
        asm volatile("global_load_dwordx4 %0, %1, off"                         \
                     : "=v"(DST) : "v"(ADDR));
    #define GPREFETCH(PR, J0)                                                  \
        {                                                                      \
            _Pragma("unroll")                                                  \
            for (int p = 0; p < 4; p++) {                                      \
                const ushort* a_ = vbase[p] + (J0);                            \
                GLOAD(PR[p], a_)                                               \
            }                                                                  \
        }
    #define GKLOAD(J0, KR)                                                     \
        {                                                                      \
            _Pragma("unroll")                                                  \
            for (int h = 0; h < 2; h++) {                                      \
                const ushort* krow = kbb + (size_t)((J0) + h * 16 + m16) * CI_; \
                const ushort* a0_ = krow + quad * 8;                           \
                const ushort* a1_ = krow + 32 + quad * 8;                      \
                GLOAD(KR[2 * h], a0_)                                          \
                GLOAD(KR[2 * h + 1], a1_)                                      \
            }                                                                  \
        }
    #define COMMIT(PR, BUF)                                                    \
        {                                                                      \
            _Pragma("unroll")                                                  \
            for (int p = 0; p < 4; p++) {                                      \
                *(us4*)&vs[BUF][p * 64 + sc][p0]     = ((const us4*)&PR[p])[0]; \
                *(us4*)&vs[BUF][p * 64 + sc][p0 + 8] = ((const us4*)&PR[p])[1]; \
            }                                                                  \
        }
    #define VWAIT(N)                                                           \
        {                                                                      \
            asm volatile("s_waitcnt vmcnt(" #N ")" ::: "memory");              \
            __builtin_amdgcn_sched_barrier(0);                                 \
        }
    // lgkm-only barrier: commits visible, global loads stay outstanding.
    #define BAR()                                                              \
        {                                                                      \
            __builtin_amdgcn_sched_barrier(0);                                 \
            asm volatile("s_waitcnt lgkmcnt(0)" ::: "memory");                 \
            __builtin_amdgcn_sched_barrier(0);                                 \
            __builtin_amdgcn_s_barrier();                                      \
            __builtin_amdgcn_sched_barrier(0);                                 \
        }
    // QK (S^T = K Q^T) for two q-groups -> exp -> pa0/pa1 ;
    // PV: each vf b128 feeds BOTH groups' MFMAs.
    #define COMPUTE(CUR, KRC)                                                  \
        {                                                                      \
            short8 pa0, pa1;                                                   \
            _Pragma("unroll")                                                  \
            for (int h = 0; h < 2; h++) {                                      \
                f32x4 T0 = (f32x4){0.f, 0.f, 0.f, 0.f};                        \
                f32x4 T1 = (f32x4){0.f, 0.f, 0.f, 0.f};                        \
                T0 = __builtin_amdgcn_mfma_f32_16x16x32_bf16(KRC[2 * h],     qf[0], T0, 0, 0, 0); \
                T0 = __builtin_amdgcn_mfma_f32_16x16x32_bf16(KRC[2 * h + 1], qf[1], T0, 0, 0, 0); \
                T1 = __builtin_amdgcn_mfma_f32_16x16x32_bf16(KRC[2 * h],     qf[2], T1, 0, 0, 0); \
                T1 = __builtin_amdgcn_mfma_f32_16x16x32_bf16(KRC[2 * h + 1], qf[3], T1, 0, 0, 0); \
                _Pragma("unroll")                                              \
                for (int r = 0; r < 4; r++) {                                  \
                    float pv0 = __expf(T0[r] - 12.0f);                         \
                    float pv1 = __expf(T1[r] - 12.0f);                         \
                    lsum0 += pv0;  lsum1 += pv1;                               \
                    pa0[h * 4 + r] = (short)f2b(pv0);                          \
                    pa1[h * 4 + r] = (short)f2b(pv1);                          \
                }                                                              \
            }                                                                  \
            __builtin_amdgcn_s_setprio(1);                                     \
            _Pragma("unroll")                                                  \
            for (int ct = 0; ct < 16; ct++) {                                  \
                short8 vf = *(const short8*)&vs[CUR][ct * 16 + m16][quad * 8]; \
                O0[ct] = __builtin_amdgcn_mfma_f32_16x16x32_bf16(pa0, vf, O0[ct], 0, 0, 0); \
                O1[ct] = __builtin_amdgcn_mfma_f32_16x16x32_bf16(pa1, vf, O1[ct], 0, 0, 0); \
            }                                                                  \
            __builtin_amdgcn_s_setprio(0);                                     \
        }

    // ---- prologue: qf (drained); V(0) staged; K(0) in flight ----
    {
        const ushort* q0 = qb + ((size_t)b * N_ + iq + m16) * CI_ + quad * 8;
        const ushort* q1 = q0 + 32;
        const ushort* q2 = qb + ((size_t)b * N_ + iq + 16 + m16) * CI_ + quad * 8;
        const ushort* q3 = q2 + 32;
        GLOAD(qf[0], q0)
        GLOAD(qf[1], q1)
        GLOAD(qf[2], q2)
        GLOAD(qf[3], q3)
        VWAIT(0)
    }
    GPREFETCH(pr, jbase)
    VWAIT(0)
    COMMIT(pr, 0)
    GKLOAD(jbase, kr[0])
    BAR()
    // entering step 0: outstanding = K(0) x4

    // Full step: issue V(st+1)+K(st+1) (on top of K(st)x4 -> 12), vmcnt(8)
    // retires K(st); compute; vmcnt(4) retires V(st+1); commit; barrier.
    // Last step: nothing issued -> vmcnt(0); compute.
    #define RUN(STEPS_)                                                        \
        _Pragma("unroll")                                                      \
        for (int st = 0; st < (STEPS_); ++st) {                                \
            const int cur = st & 1;                                            \
            const int j0_ = jbase + st * JT;                                   \
            if (st + 1 < (STEPS_)) {                                           \
                GPREFETCH(pr, j0_ + JT)                                        \
                GKLOAD(j0_ + JT, kr[cur ^ 1])                                  \
                VWAIT(8)                                                       \
            } else { VWAIT(0) }                                                \
            COMPUTE(cur, kr[cur])                                              \
            if (st + 1 < (STEPS_)) {                                           \
                VWAIT(4)                                                       \
                COMMIT(pr, cur ^ 1)                                            \
                BAR()                                                          \
            }                                                                  \
        }

    if (js == 0) { RUN(13) } else { RUN(12) }
    #undef RUN

    // ---- in-wave l reduction over quads; store both q-groups ----
    {
        float v0 = lsum0, v1 = lsum1;
        v0 += __shfl_xor(v0, 16);  v0 += __shfl_xor(v0, 32);
        v1 += __shfl_xor(v1, 16);  v1 += __shfl_xor(v1, 32);
        if (iv && lane < 16) {
            float* lpb = lp + (size_t)(b * JS + js) * N_ + i0;
            __builtin_nontemporal_store(v0, lpb + lane);
            __builtin_nontemporal_store(v1, lpb + 16 + lane);
        }
    }

    // ---- store bf16 partial O (nt: don't evict K/V from L2) ----
    if (iv) {
        ushort* opb = op + (size_t)(b * JS + js) * C_ * N_;
        #pragma unroll
        for (int ct = 0; ct < 16; ct++) {
            us4 pk0, pk1;
            pk0.x = f2b(O0[ct][0]); pk0.y = f2b(O0[ct][1]);
            pk0.z = f2b(O0[ct][2]); pk0.w = f2b(O0[ct][3]);
            pk1.x = f2b(O1[ct][0]); pk1.y = f2b(O1[ct][1]);
            pk1.z = f2b(O1[ct][2]); pk1.w = f2b(O1[ct][3]);
            ushort* row = opb + (size_t)(ct * 16 + m16) * N_ + i0 + quad * 4;
            __builtin_nontemporal_store(pk0, (us4*)row);
            __builtin_nontemporal_store(pk1, (us4*)(row + 16));
        }
    }
    #undef GLOAD
    #undef GPREFETCH
    #undef GKLOAD
    #undef COMMIT
    #undef VWAIT
    #undef BAR
    #undef COMPUTE
}

// grid 6272: thread -> (b, c, 4 consecutive i). out = gamma*Σp/Σl + x
__global__ __launch_bounds__(256)
void reduce_kernel(const ushort* __restrict__ op, const float* __restrict__ lp,
                   const float* __restrict__ x, const float* __restrict__ gamma_p,
                   float* __restrict__ out)
{
    const int g  = blockIdx.x * 256 + threadIdx.x;   // B*C*N/4 total
    const int i4 = g % (N_ / 4);
    const int c  = (g / (N_ / 4)) % C_;
    const int b  = g / ((N_ / 4) * C_);
    const size_t io = (size_t)i4 * 4;
    const float g0 = gamma_p[0];

    f32x4 acc = (f32x4){0.f, 0.f, 0.f, 0.f};
    f32x4 lt  = (f32x4){0.f, 0.f, 0.f, 0.f};
    #pragma unroll
    for (int js = 0; js < JS; js++) {
        us4 a = *(const us4*)(op + ((size_t)(b * JS + js) * C_ + c) * N_ + io);
        f32x4   l = *(const f32x4*)(lp + (size_t)(b * JS + js) * N_ + io);
        acc[0] += b2f(a.x); acc[1] += b2f(a.y); acc[2] += b2f(a.z); acc[3] += b2f(a.w);
        lt += l;
    }

    const size_t xo = ((size_t)b * C_ + c) * N_ + io;
    f32x4 xv = *(const f32x4*)(x + xo);
    f32x4 ov;
    #pragma unroll
    for (int u = 0; u < 4; u++) ov[u] = acc[u] * (g0 / lt[u]) + xv[u];
    *(f32x4*)(out + xo) = ov;
}

extern "C" void kernel_launch(void* const* d_in, const int* in_sizes, int n_in,
                              void* d_out, int out_size, void* d_ws, size_t ws_size,
                              hipStream_t stream)
{
    const float* x  = (const float*)d_in[0];
    const float* Wq = (const float*)d_in[1];
    const float* bq = (const float*)d_in[2];
    const float* Wk = (const float*)d_in[3];
    const float* bk = (const float*)d_in[4];
    const float* Wv = (const float*)d_in[5];
    const float* bv = (const float*)d_in[6];
    const float* gm = (const float*)d_in[7];
    float* out = (float*)d_out;

    ushort* qb   = (ushort*)d_ws;                    // [B][N][CI]  3.2 MB
    ushort* kb   = qb + (size_t)B_ * N_ * CI_;       // [B][N][CI]  3.2 MB
    ushort* vt   = kb + (size_t)B_ * N_ * CI_;       // [B][C][N]  12.8 MB
    ushort* xT   = vt + (size_t)B_ * C_ * N_;        // [B][N][C]  12.8 MB
    ushort* wqk  = xT + (size_t)B_ * N_ * C_;        // [128][256] 64 KB
    ushort* wv   = wqk + 128 * C_;                   // [256][256] 128 KB
    ushort* op   = wv + 256 * C_;                    // [B][JS][C][N] bf16 51.4 MB
    float*  lpf  = (float*)(op + (size_t)B_ * JS * C_ * N_);  // [B][JS][N] 401 KB

    hipLaunchKernelGGL(pre_kernel, dim3(B_ * 196 + 256), dim3(256), 0, stream,
                       x, Wq, Wk, Wv, xT, wqk, wv);
    hipLaunchKernelGGL(proj_kernel, dim3(B_ * 49), dim3(256), 0, stream,
                       xT, wqk, wv, bq, bk, bv, qb, kb, vt);
    hipLaunchKernelGGL(attn_kernel, dim3(B_ * 25 * JS), dim3(256), 0, stream,
                       qb, kb, vt, op, lpf);
    hipLaunchKernelGGL(reduce_kernel, dim3(B_ * C_ * (N_ / 4) / 256), dim3(256), 0, stream,
                       op, lpf, x, gm, out);
}

// Round 8
// 195.031 us; speedup vs baseline: 1.0784x; 1.0320x over previous
//
#include <hip/hip_runtime.h>

// PixelPropagationModule  out = gamma * (softmax(qk^T) @ v^T)^T + x
// B=8, C=256, CI=64, N=3136 (56x56), fp32 in/out.
// R13: revert attn to R11 (R12's 32q/wave collapsed concurrency: VGPR 200 ->
//      2 waves/SIMD, grid 800 -> 1.5 ragged rounds, 120us). Two fixes:
//      1) pre_kernel rewrite: old output phase wrote xT as 64-lane scattered
//         4B stores at 512B stride (~8x HBM write amplification on 12.8MB).
//         New: LDS ts2[n][72] (16B-aligned rows), both phases 16B b128 LDS
//         ops with balanced banks; xT stores are 16B, 8x128B segments/instr.
//      2) attn: REMOVE nontemporal stores. Measured: nt partial-line stores
//         bypass L2 write-combining (WRITE 58MB plain -> 96MB nt). Plain
//         stores assemble full lines in L2.
//      attn otherwise = R11 verbatim: 16q/wave, pinned asm loads, manual
//      vmcnt 8/4/0, fully unrolled RUN(13)/RUN(12), lgkm-only barrier,
//      double-buffered permuted V LDS (VSP=40: pitch must stay 16B-aligned).

constexpr int B_  = 8;
constexpr int C_  = 256;
constexpr int CI_ = 64;
constexpr int N_  = 3136;
constexpr int JS  = 4;        // attn j-split
constexpr int JT  = 32;       // attn j per step
constexpr int VSP = 40;       // V LDS row pitch (ushorts) = 80 B (16B-aligned)
constexpr int PN  = 64;       // proj pixel tile
constexpr int XSP = C_ + 8;   // proj LDS row pitch

typedef __attribute__((ext_vector_type(8))) short short8;   // 8 bf16 (4 VGPR)
typedef __attribute__((ext_vector_type(4))) float f32x4;
typedef __attribute__((ext_vector_type(4))) ushort us4;

static __device__ inline ushort f2b(float f) {               // fp32 -> bf16 (RNE)
    unsigned u = __float_as_uint(f);
    return (ushort)((u + 0x7fffu + ((u >> 16) & 1u)) >> 16);
}
static __device__ inline float b2f(ushort h) {
    return __uint_as_float(((unsigned)h) << 16);
}

// blocks [0, B_*196): x[B][C][N] f32 -> xT[B][N][C] bf16 (LDS transpose)
// blocks [B_*196, +256): Wq/Wk -> wqk[128][256], Wv -> wv[256][256] bf16
// Transpose: 64n x 64c tile. Phase 1: thread reads 8 strided floats (each
// instr: 64 lanes x 4B consecutive n = 256B coalesced), packs short8, one
// b128 LDS write (banks balanced: 4*((9n+u)%8)). Phase 2: b128 LDS read
// (balanced) -> 16B global store, 8 rows x 128B segments per instr.
__global__ __launch_bounds__(256)
void pre_kernel(const float* __restrict__ x,
                const float* __restrict__ Wq, const float* __restrict__ Wk,
                const float* __restrict__ Wv,
                ushort* __restrict__ xT, ushort* __restrict__ wqk, ushort* __restrict__ wv)
{
    __shared__ __align__(16) ushort ts2[64][72];     // 9216 B, rows 144B (16B-mult)
    const int bx  = blockIdx.x;
    const int tid = threadIdx.x;

    if (bx >= B_ * 196) {                            // weight convert
        int i = (bx - B_ * 196) * 256 + tid;
        if (i < 16384)      wqk[i] = f2b(Wq[i]);
        else if (i < 32768) wqk[i] = f2b(Wk[i - 16384]);
        wv[i] = f2b(Wv[i]);
        return;
    }

    const int b  = bx / 196;
    const int rm = bx % 196;
    const int n0 = (rm >> 2) * 64;
    const int c0 = (rm & 3) * 64;

    const float* src = x + ((size_t)b * C_ + c0) * N_ + n0;

    // Phase 1: in. 2 reps x 256 thr x 8 floats = 4096. u=c8-index, n=pixel.
    #pragma unroll
    for (int rep = 0; rep < 2; rep++) {
        const int u = rep * 4 + (tid >> 6);          // 0..7 (const per wave)
        const int n = tid & 63;
        short8 v;
        #pragma unroll
        for (int j = 0; j < 8; j++)
            v[j] = (short)f2b(src[(size_t)(u * 8 + j) * N_ + n]);
        *(short8*)&ts2[n][u * 8] = v;
    }
    __syncthreads();

    // Phase 2: out. 2 reps x 256 thr x 16B. dst row n gets 8x16B = 128B.
    ushort* dst = xT + ((size_t)b * N_ + n0) * C_ + c0;
    #pragma unroll
    for (int rep = 0; rep < 2; rep++) {
        const int e = rep * 256 + tid;
        const int n = e >> 3;                        // 0..63
        const int u = e & 7;                         // 0..7
        *(short8*)(dst + (size_t)n * C_ + u * 8) = *(const short8*)&ts2[n][u * 8];
    }
}

__global__ __launch_bounds__(256)
void proj_kernel(const ushort* __restrict__ xT, const ushort* __restrict__ wqk,
                 const ushort* __restrict__ wv,
                 const float* __restrict__ bq, const float* __restrict__ bk,
                 const float* __restrict__ bv,
                 ushort* __restrict__ qb, ushort* __restrict__ kb, ushort* __restrict__ vt)
{
    __shared__ ushort xs[PN][XSP];        // 33792 B
    const int b   = blockIdx.x / 49;
    const int n0  = (blockIdx.x % 49) * PN;
    const int tid = threadIdx.x;
    const int w    = tid >> 6;
    const int lane = tid & 63;
    const int m16  = lane & 15;
    const int quad = lane >> 4;

    // stage xT tile [64 pixels][256 c] bf16
    {
        const ushort* src = xT + ((size_t)b * N_ + n0) * C_;
        #pragma unroll
        for (int rep = 0; rep < 8; rep++) {
            int e = rep * 256 + tid;
            int row = e >> 5, ch = (e & 31) * 8;
            *(short8*)&xs[row][ch] = *(const short8*)(src + (size_t)row * C_ + ch);
        }
    }
    __syncthreads();

    // ---- QK GEMM: C[o][pixel]; waves 0,1 -> Q halves, 2,3 -> K halves ----
    {
        f32x4 acc[2][4];
        #pragma unroll
        for (int mt = 0; mt < 2; mt++)
            #pragma unroll
            for (int nt = 0; nt < 4; nt++) acc[mt][nt] = (f32x4){0.f, 0.f, 0.f, 0.f};

        #pragma unroll
        for (int kk = 0; kk < 8; kk++) {
            short8 af[2];
            #pragma unroll
            for (int mt = 0; mt < 2; mt++)   // A[m=o][k=c] = wqk row (L2-hot)
                af[mt] = *(const short8*)(wqk + (size_t)(w * 32 + mt * 16 + m16) * C_ + kk * 32 + quad * 8);
            #pragma unroll
            for (int nt = 0; nt < 4; nt++) {
                short8 bf = *(const short8*)&xs[nt * 16 + m16][kk * 32 + quad * 8];  // B[k=c][n=pix]
                #pragma unroll
                for (int mt = 0; mt < 2; mt++)
                    acc[mt][nt] = __builtin_amdgcn_mfma_f32_16x16x32_bf16(af[mt], bf, acc[mt][nt], 0, 0, 0);
            }
        }
        const float* bias = (w < 2) ? bq : bk;
        ushort* dst = (w < 2) ? qb : kb;
        const int obase = (w & 1) * 32;
        #pragma unroll
        for (int mt = 0; mt < 2; mt++) {
            f32x4 bs = *(const f32x4*)(bias + obase + mt * 16 + quad * 4);
            #pragma unroll
            for (int nt = 0; nt < 4; nt++) {
                us4 pk;
                pk.x = f2b(acc[mt][nt][0] + bs[0]);
                pk.y = f2b(acc[mt][nt][1] + bs[1]);
                pk.z = f2b(acc[mt][nt][2] + bs[2]);
                pk.w = f2b(acc[mt][nt][3] + bs[3]);
                *(us4*)(dst + ((size_t)b * N_ + n0 + nt * 16 + m16) * CI_ + obase + mt * 16 + quad * 4) = pk;
            }
        }
    }

    // ---- V GEMM: C[pixel][o]; wave w -> channels w*64..w*64+63 ----
    {
        f32x4 vacc[4][4];
        #pragma unroll
        for (int mt = 0; mt < 4; mt++)
            #pragma unroll
            for (int nt = 0; nt < 4; nt++) vacc[mt][nt] = (f32x4){0.f, 0.f, 0.f, 0.f};

        #pragma unroll
        for (int kk = 0; kk < 8; kk++) {
            short8 af[4];
            #pragma unroll
            for (int mt = 0; mt < 4; mt++)   // A[m=pix][k=c] from LDS
                af[mt] = *(const short8*)&xs[mt * 16 + m16][kk * 32 + quad * 8];
            #pragma unroll
            for (int nt = 0; nt < 4; nt++) {
                short8 bf = *(const short8*)(wv + (size_t)(w * 64 + nt * 16 + m16) * C_ + kk * 32 + quad * 8);
                #pragma unroll
                for (int mt = 0; mt < 4; mt++)
                    vacc[mt][nt] = __builtin_amdgcn_mfma_f32_16x16x32_bf16(af[mt], bf, vacc[mt][nt], 0, 0, 0);
            }
        }
        #pragma unroll
        for (int nt = 0; nt < 4; nt++) {
            int c = w * 64 + nt * 16 + m16;
            float bvc = bv[c];
            #pragma unroll
            for (int mt = 0; mt < 4; mt++) {
                us4 pk;
                pk.x = f2b(vacc[mt][nt][0] + bvc);
                pk.y = f2b(vacc[mt][nt][1] + bvc);
                pk.z = f2b(vacc[mt][nt][2] + bvc);
                pk.w = f2b(vacc[mt][nt][3] + bvc);
                *(us4*)(vt + ((size_t)b * C_ + c) * N_ + n0 + mt * 16 + quad * 4) = pk;
            }
        }
    }
}

// grid B_*49*JS = 1568. XCD swizzle: b = bx&7. Wave w: queries t*64+w*16,
// all 256 channels (16 ct). S^T = K*Q^T -> exp in-register -> A-frag pa.
// V tile [256][32] double-buffered in LDS with the PV k-perm pre-applied.
// ALL V/K loads via volatile inline-asm global_load_dwordx4 (order-pinned,
// cannot sink) + manual vmcnt. Fully unrolled static schedule -> no PHI
// copies; no VGPR cap -> no scratch (scratch would corrupt vmcnt counts).
__global__ __launch_bounds__(256)
void attn_kernel(const ushort* __restrict__ qb, const ushort* __restrict__ kb,
                 const ushort* __restrict__ vt,
                 ushort* __restrict__ op, float* __restrict__ lp)
{
    __shared__ __align__(16) ushort vs[2][C_][VSP];  // 40960 B

    const int bx   = blockIdx.x;
    const int b    = bx & 7;            // XCD-local batch
    const int rem  = bx >> 3;           // 0..195
    const int t    = rem >> 2;          // 0..48
    const int js   = rem & 3;
    const int tid  = threadIdx.x;
    const int w    = tid >> 6;
    const int lane = tid & 63;
    const int m16  = lane & 15;
    const int quad = lane >> 4;
    const int i0   = t * 64 + w * 16;

    const int jbase = ((js == 0) ? 0 : (1 + 12 * js)) * JT;  // steps 13/12

    const ushort* vtb = vt + (size_t)b * C_ * N_;
    const ushort* kbb = kb + (size_t)b * N_ * CI_;

    f32x4 O[16];
    #pragma unroll
    for (int ct = 0; ct < 16; ct++) O[ct] = (f32x4){0.f, 0.f, 0.f, 0.f};
    float lsum = 0.f;

    // staging: thread -> c row (4 thr/row), 16B global segment seg
    const int sc  = tid >> 2;
    const int seg = tid & 3;
    const int p0  = (seg & 1) * 16 + (seg >> 1) * 4;     // permuted dest base

    const ushort* vbase[4];
    #pragma unroll
    for (int p = 0; p < 4; p++)
        vbase[p] = vtb + (size_t)(p * 64 + sc) * N_ + seg * 8;

    short8 qf[2];                 // Q B-frags (loaded once, drained)
    short8 pr[2][4];              // V prefetch, 2-deep (parity-indexed, static)
    short8 kr[2][4];              // K prefetch, 1-deep (parity-indexed, static)

    #define GLOAD(DST, ADDR)                                                   \
        asm volatile("global_load_dwordx4 %0, %1, off"                         \
                     : "=v"(DST) : "v"(ADDR));
    #define GPREFETCH(PR, J0)                                                  \
        {                                                                      \
            _Pragma("unroll")                                                  \
            for (int p = 0; p < 4; p++) {                                      \
                const ushort* a_ = vbase[p] + (J0);                            \
                GLOAD(PR[p], a_)                                               \
            }                                                                  \
        }
    #define GKLOAD(J0, KR)                                                     \
        {                                                                      \
            _Pragma("unroll")                                                  \
            for (int h = 0; h < 2; h++) {                                      \
                const ushort* krow = kbb + (size_t)((J0) + h * 16 + m16) * CI_; \
                const ushort* a0_ = krow + quad * 8;                           \
                const ushort* a1_ = krow + 32 + quad * 8;                      \
                GLOAD(KR[2 * h], a0_)                                          \
                GLOAD(KR[2 * h + 1], a1_)                                      \
            }                                                                  \
        }
    #define COMMIT(PR, BUF)                                                    \
        {                                                                      \
            _Pragma("unroll")                                                  \
            for (int p = 0; p < 4; p++) {                                      \
                *(us4*)&vs[BUF][p * 64 + sc][p0]     = ((const us4*)&PR[p])[0]; \
                *(us4*)&vs[BUF][p * 64 + sc][p0 + 8] = ((const us4*)&PR[p])[1]; \
            }                                                                  \
        }
    #define VWAIT(N)                                                           \
        {                                                                      \
            asm volatile("s_waitcnt vmcnt(" #N ")" ::: "memory");              \
            __builtin_amdgcn_sched_barrier(0);                                 \
        }
    // lgkm-only barrier: commits visible, global loads stay outstanding.
    #define BAR()                                                              \
        {                                                                      \
            __builtin_amdgcn_sched_barrier(0);                                 \
            asm volatile("s_waitcnt lgkmcnt(0)" ::: "memory");                 \
            __builtin_amdgcn_sched_barrier(0);                                 \
            __builtin_amdgcn_s_barrier();                                      \
            __builtin_amdgcn_sched_barrier(0);                                 \
        }
    // QK (S^T = K Q^T) -> exp -> pa ; PV over all 256 ch from vs[CUR]
    #define COMPUTE(CUR, KRC)                                                  \
        {                                                                      \
            short8 pa;                                                         \
            _Pragma("unroll")                                                  \
            for (int h = 0; h < 2; h++) {                                      \
                f32x4 T = (f32x4){0.f, 0.f, 0.f, 0.f};                         \
                T = __builtin_amdgcn_mfma_f32_16x16x32_bf16(KRC[2 * h],     qf[0], T, 0, 0, 0); \
                T = __builtin_amdgcn_mfma_f32_16x16x32_bf16(KRC[2 * h + 1], qf[1], T, 0, 0, 0); \
                _Pragma("unroll")                                              \
                for (int r = 0; r < 4; r++) {                                  \
                    float pv = __expf(T[r] - 12.0f);   /* static shift */      \
                    lsum += pv;                                                \
                    pa[h * 4 + r] = (short)f2b(pv);                            \
                }                                                              \
            }                                                                  \
            __builtin_amdgcn_s_setprio(1);                                     \
            _Pragma("unroll")                                                  \
            for (int ct = 0; ct < 16; ct++) {                                  \
                short8 vf = *(const short8*)&vs[CUR][ct * 16 + m16][quad * 8]; \
                O[ct] = __builtin_amdgcn_mfma_f32_16x16x32_bf16(pa, vf, O[ct], 0, 0, 0); \
            }                                                                  \
            __builtin_amdgcn_s_setprio(0);                                     \
        }

    // ---- prologue: qf (drained), then V(0),V(1),K(0) pinned in flight ----
    {
        const ushort* qbase = qb + ((size_t)b * N_ + i0 + m16) * CI_;
        const ushort* qa0 = qbase + quad * 8;
        const ushort* qa1 = qbase + 32 + quad * 8;
        GLOAD(qf[0], qa0)
        GLOAD(qf[1], qa1)
        VWAIT(0)
    }
    GPREFETCH(pr[0], jbase)
    GPREFETCH(pr[1], jbase + JT)
    GKLOAD(jbase, kr[0])
    VWAIT(8)                               // retire pr[0] (oldest 4 of 12)
    COMMIT(pr[0], 0)
    BAR()
    // entering step 0: outstanding = {V(1) in pr[1], K(0) in kr[0]} = 8

    // Fully-unrolled schedule; all conditions constant-fold per iteration.
    // Full step (st+2<S):  issue V(st+2)->pr[cur], K(st+1)->kr[cur^1];
    //   16 outstanding -> vmcnt(8) retires V(st+1)+K(st).
    // Epi1 (st==S-2): issue K only; 12 outstanding -> vmcnt(4).
    // Epi2 (st==S-1): nothing issued -> vmcnt(0).
    #define RUN(STEPS_)                                                        \
        _Pragma("unroll")                                                      \
        for (int st = 0; st < (STEPS_); ++st) {                                \
            const int cur = st & 1;                                            \
            const int j0_ = jbase + st * JT;                                   \
            if (st + 2 < (STEPS_)) GPREFETCH(pr[cur], j0_ + 2 * JT)            \
            if (st + 1 < (STEPS_)) GKLOAD(j0_ + JT, kr[cur ^ 1])               \
            if (st + 2 < (STEPS_)) { VWAIT(8) }                                \
            else if (st + 1 < (STEPS_)) { VWAIT(4) }                           \
            else { VWAIT(0) }                                                  \
            COMPUTE(cur, kr[cur])                                              \
            if (st + 1 < (STEPS_)) {                                           \
                COMMIT(pr[cur ^ 1], cur ^ 1)                                   \
                BAR()                                                          \
            }                                                                  \
        }

    if (js == 0) { RUN(13) } else { RUN(12) }
    #undef RUN

    // ---- in-wave l reduction over quads; every wave owns unique 16 q ----
    {
        float v = lsum;
        v += __shfl_xor(v, 16);
        v += __shfl_xor(v, 32);
        if (lane < 16)
            lp[(size_t)(b * JS + js) * N_ + i0 + lane] = v;
    }

    // ---- store bf16 partial O (plain stores: L2 assembles full lines) ----
    ushort* opb = op + (size_t)(b * JS + js) * C_ * N_;
    #pragma unroll
    for (int ct = 0; ct < 16; ct++) {
        us4 pk;
        pk.x = f2b(O[ct][0]);
        pk.y = f2b(O[ct][1]);
        pk.z = f2b(O[ct][2]);
        pk.w = f2b(O[ct][3]);
        *(us4*)(opb + (size_t)(ct * 16 + m16) * N_ + i0 + quad * 4) = pk;
    }
    #undef GLOAD
    #undef GPREFETCH
    #undef GKLOAD
    #undef COMMIT
    #undef VWAIT
    #undef BAR
    #undef COMPUTE
}

// grid 6272: thread -> (b, c, 4 consecutive i). out = gamma*Σp/Σl + x
__global__ __launch_bounds__(256)
void reduce_kernel(const ushort* __restrict__ op, const float* __restrict__ lp,
                   const float* __restrict__ x, const float* __restrict__ gamma_p,
                   float* __restrict__ out)
{
    const int g  = blockIdx.x * 256 + threadIdx.x;   // B*C*N/4 total
    const int i4 = g % (N_ / 4);
    const int c  = (g / (N_ / 4)) % C_;
    const int b  = g / ((N_ / 4) * C_);
    const size_t io = (size_t)i4 * 4;
    const float g0 = gamma_p[0];

    f32x4 acc = (f32x4){0.f, 0.f, 0.f, 0.f};
    f32x4 lt  = (f32x4){0.f, 0.f, 0.f, 0.f};
    #pragma unroll
    for (int js = 0; js < JS; js++) {
        us4 a = *(const us4*)(op + ((size_t)(b * JS + js) * C_ + c) * N_ + io);
        f32x4   l = *(const f32x4*)(lp + (size_t)(b * JS + js) * N_ + io);
        acc[0] += b2f(a.x); acc[1] += b2f(a.y); acc[2] += b2f(a.z); acc[3] += b2f(a.w);
        lt += l;
    }

    const size_t xo = ((size_t)b * C_ + c) * N_ + io;
    f32x4 xv = *(const f32x4*)(x + xo);
    f32x4 ov;
    #pragma unroll
    for (int u = 0; u < 4; u++) ov[u] = acc[u] * (g0 / lt[u]) + xv[u];
    *(f32x4*)(out + xo) = ov;
}

extern "C" void kernel_launch(void* const* d_in, const int* in_sizes, int n_in,
                              void* d_out, int out_size, void* d_ws, size_t ws_size,
                              hipStream_t stream)
{
    const float* x  = (const float*)d_in[0];
    const float* Wq = (const float*)d_in[1];
    const float* bq = (const float*)d_in[2];
    const float* Wk = (const float*)d_in[3];
    const float* bk = (const float*)d_in[4];
    const float* Wv = (const float*)d_in[5];
    const float* bv = (const float*)d_in[6];
    const float* gm = (const float*)d_in[7];
    float* out = (float*)d_out;

    ushort* qb   = (ushort*)d_ws;                    // [B][N][CI]  3.2 MB
    ushort* kb   = qb + (size_t)B_ * N_ * CI_;       // [B][N][CI]  3.2 MB
    ushort* vt   = kb + (size_t)B_ * N_ * CI_;       // [B][C][N]  12.8 MB
    ushort* xT   = vt + (size_t)B_ * C_ * N_;        // [B][N][C]  12.8 MB
    ushort* wqk  = xT + (size_t)B_ * N_ * C_;        // [128][256] 64 KB
    ushort* wv   = wqk + 128 * C_;                   // [256][256] 128 KB
    ushort* op   = wv + 256 * C_;                    // [B][JS][C][N] bf16 51.4 MB
    float*  lpf  = (float*)(op + (size_t)B_ * JS * C_ * N_);  // [B][JS][N] 401 KB

    hipLaunchKernelGGL(pre_kernel, dim3(B_ * 196 + 256), dim3(256), 0, stream,
                       x, Wq, Wk, Wv, xT, wqk, wv);
    hipLaunchKernelGGL(proj_kernel, dim3(B_ * 49), dim3(256), 0, stream,
                       xT, wqk, wv, bq, bk, bv, qb, kb, vt);
    hipLaunchKernelGGL(attn_kernel, dim3(B_ * 49 * JS), dim3(256), 0, stream,
                       qb, kb, vt, op, lpf);
    hipLaunchKernelGGL(reduce_kernel, dim3(B_ * C_ * (N_ / 4) / 256), dim3(256), 0, stream,
                       op, lpf, x, gm, out);
}

// Round 9
// 188.306 us; speedup vs baseline: 1.1169x; 1.0357x over previous
//
#include <hip/hip_runtime.h>

// PixelPropagationModule  out = gamma * (softmax(qk^T) @ v^T)^T + x
// B=8, C=256, CI=64, N=3136 (56x56), fp32 in/out.
// R14: pipeline-level dataflow cuts. R13 post-mortem: attn 81us but total
//      195us -> ~114us outside attn vs ~45us roofline. Two cuts:
//      1) FUSE transpose into proj: xT (12.8MB write + 12.8MB read) existed
//         only to feed proj's xs tile. proj now reads x fp32 directly
//         (coalesced 256B row-chunks) and transposes into xs in LDS.
//         pre shrinks to a 256-block weight-convert kernel.
//      2) JS 4->2: attn grid 784 = 3.06 blocks/CU (exactly the 3-block LDS
//         residency; was 2 ragged generations), prologue drains halve,
//         op/lp partial traffic halves in attn AND reduce (51.4->25.7MB
//         each way). Steps 25+24 cover the same j-range; numerics identical.
//      attn core = R13: pinned asm loads, manual vmcnt 8/4/0, full unroll,
//      lgkm-only barrier, double-buffered permuted V LDS, plain stores.
//      Prologue micro-fix: no separate qf drain; qf+V0+V1+K0 = 14 in
//      flight, one vmcnt(8) retires qf+V0 -> invariant preserved.

constexpr int B_  = 8;
constexpr int C_  = 256;
constexpr int CI_ = 64;
constexpr int N_  = 3136;
constexpr int JS  = 2;        // attn j-split
constexpr int JT  = 32;       // attn j per step
constexpr int VSP = 40;       // V LDS row pitch (ushorts) = 80 B (16B-aligned)
constexpr int PN  = 64;       // proj pixel tile
constexpr int XSP = C_ + 8;   // proj LDS row pitch

typedef __attribute__((ext_vector_type(8))) short short8;   // 8 bf16 (4 VGPR)
typedef __attribute__((ext_vector_type(4))) float f32x4;
typedef __attribute__((ext_vector_type(4))) ushort us4;

static __device__ inline ushort f2b(float f) {               // fp32 -> bf16 (RNE)
    unsigned u = __float_as_uint(f);
    return (ushort)((u + 0x7fffu + ((u >> 16) & 1u)) >> 16);
}
static __device__ inline float b2f(ushort h) {
    return __uint_as_float(((unsigned)h) << 16);
}

// grid 256: Wq/Wk -> wqk[128][256], Wv -> wv[256][256] bf16
__global__ __launch_bounds__(256)
void weights_kernel(const float* __restrict__ Wq, const float* __restrict__ Wk,
                    const float* __restrict__ Wv,
                    ushort* __restrict__ wqk, ushort* __restrict__ wv)
{
    int i = blockIdx.x * 256 + threadIdx.x;
    if (i < 16384)      wqk[i] = f2b(Wq[i]);
    else if (i < 32768) wqk[i] = f2b(Wk[i - 16384]);
    wv[i] = f2b(Wv[i]);
}

// grid B_*49: block (b, 64-pixel tile). Transposes x[b,:,n0..n0+64] fp32
// into xs[64][256] bf16 in LDS (phase 1), then QK / V projection GEMMs.
__global__ __launch_bounds__(256)
void proj_kernel(const float* __restrict__ x, const ushort* __restrict__ wqk,
                 const ushort* __restrict__ wv,
                 const float* __restrict__ bq, const float* __restrict__ bk,
                 const float* __restrict__ bv,
                 ushort* __restrict__ qb, ushort* __restrict__ kb, ushort* __restrict__ vt)
{
    __shared__ __align__(16) ushort xs[PN][XSP];     // 33792 B
    const int b   = blockIdx.x / 49;
    const int n0  = (blockIdx.x % 49) * PN;
    const int tid = threadIdx.x;
    const int w    = tid >> 6;
    const int lane = tid & 63;
    const int m16  = lane & 15;
    const int quad = lane >> 4;

    // ---- transpose-in: 8 reps x (256 thr x 8 floats) = 64n x 256c ----
    // Each inner load: 64 lanes x 4B consecutive n = 256B coalesced chunk.
    {
        const float* xsrc = x + (size_t)b * C_ * N_ + n0;
        #pragma unroll
        for (int rep = 0; rep < 8; rep++) {
            const int u = rep * 4 + w;               // c8-group 0..31
            short8 v;
            #pragma unroll
            for (int j = 0; j < 8; j++)
                v[j] = (short)f2b(xsrc[(size_t)(u * 8 + j) * N_ + lane]);
            *(short8*)&xs[lane][u * 8] = v;
        }
    }
    __syncthreads();

    // ---- QK GEMM: C[o][pixel]; waves 0,1 -> Q halves, 2,3 -> K halves ----
    {
        f32x4 acc[2][4];
        #pragma unroll
        for (int mt = 0; mt < 2; mt++)
            #pragma unroll
            for (int nt = 0; nt < 4; nt++) acc[mt][nt] = (f32x4){0.f, 0.f, 0.f, 0.f};

        #pragma unroll
        for (int kk = 0; kk < 8; kk++) {
            short8 af[2];
            #pragma unroll
            for (int mt = 0; mt < 2; mt++)   // A[m=o][k=c] = wqk row (L2-hot)
                af[mt] = *(const short8*)(wqk + (size_t)(w * 32 + mt * 16 + m16) * C_ + kk * 32 + quad * 8);
            #pragma unroll
            for (int nt = 0; nt < 4; nt++) {
                short8 bf = *(const short8*)&xs[nt * 16 + m16][kk * 32 + quad * 8];  // B[k=c][n=pix]
                #pragma unroll
                for (int mt = 0; mt < 2; mt++)
                    acc[mt][nt] = __builtin_amdgcn_mfma_f32_16x16x32_bf16(af[mt], bf, acc[mt][nt], 0, 0, 0);
            }
        }
        const float* bias = (w < 2) ? bq : bk;
        ushort* dst = (w < 2) ? qb : kb;
        const int obase = (w & 1) * 32;
        #pragma unroll
        for (int mt = 0; mt < 2; mt++) {
            f32x4 bs = *(const f32x4*)(bias + obase + mt * 16 + quad * 4);
            #pragma unroll
            for (int nt = 0; nt < 4; nt++) {
                us4 pk;
                pk.x = f2b(acc[mt][nt][0] + bs[0]);
                pk.y = f2b(acc[mt][nt][1] + bs[1]);
                pk.z = f2b(acc[mt][nt][2] + bs[2]);
                pk.w = f2b(acc[mt][nt][3] + bs[3]);
                *(us4*)(dst + ((size_t)b * N_ + n0 + nt * 16 + m16) * CI_ + obase + mt * 16 + quad * 4) = pk;
            }
        }
    }

    // ---- V GEMM: C[pixel][o]; wave w -> channels w*64..w*64+63 ----
    {
        f32x4 vacc[4][4];
        #pragma unroll
        for (int mt = 0; mt < 4; mt++)
            #pragma unroll
            for (int nt = 0; nt < 4; nt++) vacc[mt][nt] = (f32x4){0.f, 0.f, 0.f, 0.f};

        #pragma unroll
        for (int kk = 0; kk < 8; kk++) {
            short8 af[4];
            #pragma unroll
            for (int mt = 0; mt < 4; mt++)   // A[m=pix][k=c] from LDS
                af[mt] = *(const short8*)&xs[mt * 16 + m16][kk * 32 + quad * 8];
            #pragma unroll
            for (int nt = 0; nt < 4; nt++) {
                short8 bf = *(const short8*)(wv + (size_t)(w * 64 + nt * 16 + m16) * C_ + kk * 32 + quad * 8);
                #pragma unroll
                for (int mt = 0; mt < 4; mt++)
                    vacc[mt][nt] = __builtin_amdgcn_mfma_f32_16x16x32_bf16(af[mt], bf, vacc[mt][nt], 0, 0, 0);
            }
        }
        #pragma unroll
        for (int nt = 0; nt < 4; nt++) {
            int c = w * 64 + nt * 16 + m16;
            float bvc = bv[c];
            #pragma unroll
            for (int mt = 0; mt < 4; mt++) {
                us4 pk;
                pk.x = f2b(vacc[mt][nt][0] + bvc);
                pk.y = f2b(vacc[mt][nt][1] + bvc);
                pk.z = f2b(vacc[mt][nt][2] + bvc);
                pk.w = f2b(vacc[mt][nt][3] + bvc);
                *(us4*)(vt + ((size_t)b * C_ + c) * N_ + n0 + mt * 16 + quad * 4) = pk;
            }
        }
    }
}

// grid B_*49*JS = 784. XCD swizzle: b = bx&7; rem = bx>>3: t = rem>>1,
// js = rem&1. Wave w: queries t*64+w*16, all 256 channels (16 ct).
// S^T = K*Q^T -> exp in-register -> A-frag pa. V tile [256][32] double-
// buffered in LDS with the PV k-perm pre-applied. ALL V/K loads via pinned
// volatile asm global_load_dwordx4 + manual vmcnt; fully unrolled schedule
// (no PHI copies, no VGPR cap -> no scratch).
__global__ __launch_bounds__(256)
void attn_kernel(const ushort* __restrict__ qb, const ushort* __restrict__ kb,
                 const ushort* __restrict__ vt,
                 ushort* __restrict__ op, float* __restrict__ lp)
{
    __shared__ __align__(16) ushort vs[2][C_][VSP];  // 40960 B

    const int bx   = blockIdx.x;
    const int b    = bx & 7;            // XCD-local batch
    const int rem  = bx >> 3;           // 0..97
    const int t    = rem >> 1;          // 0..48
    const int js   = rem & 1;
    const int tid  = threadIdx.x;
    const int w    = tid >> 6;
    const int lane = tid & 63;
    const int m16  = lane & 15;
    const int quad = lane >> 4;
    const int i0   = t * 64 + w * 16;

    const int jbase = (js == 0) ? 0 : 25 * JT;       // steps 25/24

    const ushort* vtb = vt + (size_t)b * C_ * N_;
    const ushort* kbb = kb + (size_t)b * N_ * CI_;

    f32x4 O[16];
    #pragma unroll
    for (int ct = 0; ct < 16; ct++) O[ct] = (f32x4){0.f, 0.f, 0.f, 0.f};
    float lsum = 0.f;

    // staging: thread -> c row (4 thr/row), 16B global segment seg
    const int sc  = tid >> 2;
    const int seg = tid & 3;
    const int p0  = (seg & 1) * 16 + (seg >> 1) * 4;     // permuted dest base

    const ushort* vbase[4];
    #pragma unroll
    for (int p = 0; p < 4; p++)
        vbase[p] = vtb + (size_t)(p * 64 + sc) * N_ + seg * 8;

    short8 qf[2];                 // Q B-frags (loaded once)
    short8 pr[2][4];              // V prefetch, 2-deep (parity-indexed, static)
    short8 kr[2][4];              // K prefetch, 1-deep (parity-indexed, static)

    #define GLOAD(DST, ADDR)                                                   \
        asm volatile("global_load_dwordx4 %0, %1, off"                         \
                     : "=v"(DST) : "v"(ADDR));
    #define GPREFETCH(PR, J0)                                                  \
        {                                                                      \
            _Pragma("unroll")                                                  \
            for (int p = 0; p < 4; p++) {                                      \
                const ushort* a_ = vbase[p] + (J0);                            \
                GLOAD(PR[p], a_)                                               \
            }                                                                  \
        }
    #define GKLOAD(J0, KR)                                                     \
        {                                                                      \
            _Pragma("unroll")                                                  \
            for (int h = 0; h < 2; h++) {                                      \
                const ushort* krow = kbb + (size_t)((J0) + h * 16 + m16) * CI_; \
                const ushort* a0_ = krow + quad * 8;                           \
                const ushort* a1_ = krow + 32 + quad * 8;                      \
                GLOAD(KR[2 * h], a0_)                                          \
                GLOAD(KR[2 * h + 1], a1_)                                      \
            }                                                                  \
        }
    #define COMMIT(PR, BUF)                                                    \
        {                                                                      \
            _Pragma("unroll")                                                  \
            for (int p = 0; p < 4; p++) {                                      \
                *(us4*)&vs[BUF][p * 64 + sc][p0]     = ((const us4*)&PR[p])[0]; \
                *(us4*)&vs[BUF][p * 64 + sc][p0 + 8] = ((const us4*)&PR[p])[1]; \
            }                                                                  \
        }
    #define VWAIT(N)                                                           \
        {                                                                      \
            asm volatile("s_waitcnt vmcnt(" #N ")" ::: "memory");              \
            __builtin_amdgcn_sched_barrier(0);                                 \
        }
    // lgkm-only barrier: commits visible, global loads stay outstanding.
    #define BAR()                                                              \
        {                                                                      \
            __builtin_amdgcn_sched_barrier(0);                                 \
            asm volatile("s_waitcnt lgkmcnt(0)" ::: "memory");                 \
            __builtin_amdgcn_sched_barrier(0);                                 \
            __builtin_amdgcn_s_barrier();                                      \
            __builtin_amdgcn_sched_barrier(0);                                 \
        }
    // QK (S^T = K Q^T) -> exp -> pa ; PV over all 256 ch from vs[CUR]
    #define COMPUTE(CUR, KRC)                                                  \
        {                                                                      \
            short8 pa;                                                         \
            _Pragma("unroll")                                                  \
            for (int h = 0; h < 2; h++) {                                      \
                f32x4 T = (f32x4){0.f, 0.f, 0.f, 0.f};                         \
                T = __builtin_amdgcn_mfma_f32_16x16x32_bf16(KRC[2 * h],     qf[0], T, 0, 0, 0); \
                T = __builtin_amdgcn_mfma_f32_16x16x32_bf16(KRC[2 * h + 1], qf[1], T, 0, 0, 0); \
                _Pragma("unroll")                                              \
                for (int r = 0; r < 4; r++) {                                  \
                    float pv = __expf(T[r] - 12.0f);   /* static shift */      \
                    lsum += pv;                                                \
                    pa[h * 4 + r] = (short)f2b(pv);                            \
                }                                                              \
            }                                                                  \
            __builtin_amdgcn_s_setprio(1);                                     \
            _Pragma("unroll")                                                  \
            for (int ct = 0; ct < 16; ct++) {                                  \
                short8 vf = *(const short8*)&vs[CUR][ct * 16 + m16][quad * 8]; \
                O[ct] = __builtin_amdgcn_mfma_f32_16x16x32_bf16(pa, vf, O[ct], 0, 0, 0); \
            }                                                                  \
            __builtin_amdgcn_s_setprio(0);                                     \
        }

    // ---- prologue: qf,V(0),V(1),K(0) all in flight; one vmcnt(8) retires
    //      the oldest 6 (qf + V(0)); invariant {V(1),K(0)}=8 preserved ----
    {
        const ushort* qbase = qb + ((size_t)b * N_ + i0 + m16) * CI_;
        const ushort* qa0 = qbase + quad * 8;
        const ushort* qa1 = qbase + 32 + quad * 8;
        GLOAD(qf[0], qa0)
        GLOAD(qf[1], qa1)
    }
    GPREFETCH(pr[0], jbase)
    GPREFETCH(pr[1], jbase + JT)
    GKLOAD(jbase, kr[0])
    VWAIT(8)                               // retire qf(2) + pr[0](4)
    COMMIT(pr[0], 0)
    BAR()
    // entering step 0: outstanding = {V(1) in pr[1], K(0) in kr[0]} = 8

    // Fully-unrolled schedule; all conditions constant-fold per iteration.
    // Full step (st+2<S):  issue V(st+2)->pr[cur], K(st+1)->kr[cur^1];
    //   16 outstanding -> vmcnt(8) retires V(st+1)+K(st).
    // Epi1 (st==S-2): issue K only; 12 outstanding -> vmcnt(4).
    // Epi2 (st==S-1): nothing issued -> vmcnt(0).
    #define RUN(STEPS_)                                                        \
        _Pragma("unroll")                                                      \
        for (int st = 0; st < (STEPS_); ++st) {                                \
            const int cur = st & 1;                                            \
            const int j0_ = jbase + st * JT;                                   \
            if (st + 2 < (STEPS_)) GPREFETCH(pr[cur], j0_ + 2 * JT)            \
            if (st + 1 < (STEPS_)) GKLOAD(j0_ + JT, kr[cur ^ 1])               \
            if (st + 2 < (STEPS_)) { VWAIT(8) }                                \
            else if (st + 1 < (STEPS_)) { VWAIT(4) }                           \
            else { VWAIT(0) }                                                  \
            COMPUTE(cur, kr[cur])                                              \
            if (st + 1 < (STEPS_)) {                                           \
                COMMIT(pr[cur ^ 1], cur ^ 1)                                   \
                BAR()                                                          \
            }                                                                  \
        }

    if (js == 0) { RUN(25) } else { RUN(24) }
    #undef RUN

    // ---- in-wave l reduction over quads; every wave owns unique 16 q ----
    {
        float v = lsum;
        v += __shfl_xor(v, 16);
        v += __shfl_xor(v, 32);
        if (lane < 16)
            lp[(size_t)(b * JS + js) * N_ + i0 + lane] = v;
    }

    // ---- store bf16 partial O (plain stores: L2 assembles full lines) ----
    ushort* opb = op + (size_t)(b * JS + js) * C_ * N_;
    #pragma unroll
    for (int ct = 0; ct < 16; ct++) {
        us4 pk;
        pk.x = f2b(O[ct][0]);
        pk.y = f2b(O[ct][1]);
        pk.z = f2b(O[ct][2]);
        pk.w = f2b(O[ct][3]);
        *(us4*)(opb + (size_t)(ct * 16 + m16) * N_ + i0 + quad * 4) = pk;
    }
    #undef GLOAD
    #undef GPREFETCH
    #undef GKLOAD
    #undef COMMIT
    #undef VWAIT
    #undef BAR
    #undef COMPUTE
}

// grid 6272: thread -> (b, c, 4 consecutive i). out = gamma*Σp/Σl + x
__global__ __launch_bounds__(256)
void reduce_kernel(const ushort* __restrict__ op, const float* __restrict__ lp,
                   const float* __restrict__ x, const float* __restrict__ gamma_p,
                   float* __restrict__ out)
{
    const int g  = blockIdx.x * 256 + threadIdx.x;   // B*C*N/4 total
    const int i4 = g % (N_ / 4);
    const int c  = (g / (N_ / 4)) % C_;
    const int b  = g / ((N_ / 4) * C_);
    const size_t io = (size_t)i4 * 4;
    const float g0 = gamma_p[0];

    f32x4 acc = (f32x4){0.f, 0.f, 0.f, 0.f};
    f32x4 lt  = (f32x4){0.f, 0.f, 0.f, 0.f};
    #pragma unroll
    for (int js = 0; js < JS; js++) {
        us4 a = *(const us4*)(op + ((size_t)(b * JS + js) * C_ + c) * N_ + io);
        f32x4   l = *(const f32x4*)(lp + (size_t)(b * JS + js) * N_ + io);
        acc[0] += b2f(a.x); acc[1] += b2f(a.y); acc[2] += b2f(a.z); acc[3] += b2f(a.w);
        lt += l;
    }

    const size_t xo = ((size_t)b * C_ + c) * N_ + io;
    f32x4 xv = *(const f32x4*)(x + xo);
    f32x4 ov;
    #pragma unroll
    for (int u = 0; u < 4; u++) ov[u] = acc[u] * (g0 / lt[u]) + xv[u];
    *(f32x4*)(out + xo) = ov;
}

extern "C" void kernel_launch(void* const* d_in, const int* in_sizes, int n_in,
                              void* d_out, int out_size, void* d_ws, size_t ws_size,
                              hipStream_t stream)
{
    const float* x  = (const float*)d_in[0];
    const float* Wq = (const float*)d_in[1];
    const float* bq = (const float*)d_in[2];
    const float* Wk = (const float*)d_in[3];
    const float* bk = (const float*)d_in[4];
    const float* Wv = (const float*)d_in[5];
    const float* bv = (const float*)d_in[6];
    const float* gm = (const float*)d_in[7];
    float* out = (float*)d_out;

    ushort* qb   = (ushort*)d_ws;                    // [B][N][CI]  3.2 MB
    ushort* kb   = qb + (size_t)B_ * N_ * CI_;       // [B][N][CI]  3.2 MB
    ushort* vt   = kb + (size_t)B_ * N_ * CI_;       // [B][C][N]  12.8 MB
    ushort* wqk  = vt + (size_t)B_ * C_ * N_;        // [128][256] 64 KB
    ushort* wv   = wqk + 128 * C_;                   // [256][256] 128 KB
    ushort* op   = wv + 256 * C_;                    // [B][JS][C][N] bf16 25.7 MB
    float*  lpf  = (float*)(op + (size_t)B_ * JS * C_ * N_);  // [B][JS][N] 200 KB

    hipLaunchKernelGGL(weights_kernel, dim3(256), dim3(256), 0, stream,
                       Wq, Wk, Wv, wqk, wv);
    hipLaunchKernelGGL(proj_kernel, dim3(B_ * 49), dim3(256), 0, stream,
                       x, wqk, wv, bq, bk, bv, qb, kb, vt);
    hipLaunchKernelGGL(attn_kernel, dim3(B_ * 49 * JS), dim3(256), 0, stream,
                       qb, kb, vt, op, lpf);
    hipLaunchKernelGGL(reduce_kernel, dim3(B_ * C_ * (N_ / 4) / 256), dim3(256), 0, stream,
                       op, lpf, x, gm, out);
}